// Round 1
// baseline (3287.066 us; speedup 1.0000x reference)
//
#include <hip/hip_runtime.h>
#include <hip/hip_bf16.h>

// Problem constants
#define E0   500000
#define NS   50000
#define NT   50000
#define NND  100000
#define DD   128
#define ETOT (2*E0 + NS)   // per-conv edge count incl. in-range self loops = 1,050,000

// workspace layout (in floats)
#define OFF_H1   0UL
#define OFF_H2   12800000UL
#define OFF_AS1  25600000UL
#define OFF_AD1  25700000UL
#define OFF_AS2  25800000UL
#define OFF_AD2  25900000UL
#define OFF_DEN1 26000000UL
#define OFF_DEN2 26050000UL
#define OFF_EE1  26100000UL
#define OFF_EE2  27150000UL
// total 28,200,000 floats = 112.8 MB

// ---------------------------------------------------------------------------
// Fused dense kernel: x = xin@W0.T + b0 ; h = x@W1.T (store) ; h2 = x@W2.T
// (store); attention dots a_s = h·a_src, a_d = h·a_dst fused into epilogues.
// Block: 256 threads, 32 rows. LDS: W[k][j] (pad 132), X[k][r] (pad 33).
// ---------------------------------------------------------------------------
__device__ __forceinline__ void stage_w(float* Wl, const float* __restrict__ W, int tid) {
    for (int idx = tid; idx < 128 * 128; idx += 256) {
        int j = idx >> 7, k = idx & 127;
        Wl[k * 132 + j] = W[idx];
    }
}

__device__ __forceinline__ void gemm_phase(const float* Wl, const float* Xl,
                                           int tr, int tc, float acc[16]) {
#pragma unroll
    for (int i = 0; i < 16; i++) acc[i] = 0.f;
#pragma unroll 8
    for (int k = 0; k < 128; k++) {
        const float4 w4 = *(const float4*)(Wl + k * 132 + tc * 4);
        const float x0 = Xl[k * 33 + tr * 4 + 0];
        const float x1 = Xl[k * 33 + tr * 4 + 1];
        const float x2 = Xl[k * 33 + tr * 4 + 2];
        const float x3 = Xl[k * 33 + tr * 4 + 3];
        acc[0]  += x0 * w4.x; acc[1]  += x0 * w4.y; acc[2]  += x0 * w4.z; acc[3]  += x0 * w4.w;
        acc[4]  += x1 * w4.x; acc[5]  += x1 * w4.y; acc[6]  += x1 * w4.z; acc[7]  += x1 * w4.w;
        acc[8]  += x2 * w4.x; acc[9]  += x2 * w4.y; acc[10] += x2 * w4.z; acc[11] += x2 * w4.w;
        acc[12] += x3 * w4.x; acc[13] += x3 * w4.y; acc[14] += x3 * w4.z; acc[15] += x3 * w4.w;
    }
}

__device__ __forceinline__ void epilogue_store(const float acc[16], int half, int row0,
                                               int tr, int tc,
                                               const float* __restrict__ av_s,
                                               const float* __restrict__ av_d,
                                               float* __restrict__ h,
                                               float* __restrict__ as_,
                                               float* __restrict__ ad_) {
    float a_sv[4], a_dv[4];
#pragma unroll
    for (int c = 0; c < 4; c++) { a_sv[c] = av_s[tc * 4 + c]; a_dv[c] = av_d[tc * 4 + c]; }
#pragma unroll
    for (int rr = 0; rr < 4; rr++) {
        const int gr = row0 + tr * 4 + rr;
        const bool ok = (gr < NS);
        const int node = half * NS + gr;
        if (ok) {
            *(float4*)(h + (size_t)node * DD + tc * 4) =
                make_float4(acc[rr * 4 + 0], acc[rr * 4 + 1], acc[rr * 4 + 2], acc[rr * 4 + 3]);
        }
        float ps = acc[rr * 4 + 0] * a_sv[0] + acc[rr * 4 + 1] * a_sv[1] +
                   acc[rr * 4 + 2] * a_sv[2] + acc[rr * 4 + 3] * a_sv[3];
        float pd = acc[rr * 4 + 0] * a_dv[0] + acc[rr * 4 + 1] * a_dv[1] +
                   acc[rr * 4 + 2] * a_dv[2] + acc[rr * 4 + 3] * a_dv[3];
#pragma unroll
        for (int m = 16; m; m >>= 1) { ps += __shfl_xor(ps, m); pd += __shfl_xor(pd, m); }
        if (ok && tc == 0) { as_[node] = ps; ad_[node] = pd; }
    }
}

__global__ __launch_bounds__(256, 1) void k_gemm(
    const float* __restrict__ xs, const float* __restrict__ xt,
    const float* __restrict__ Ws, const float* __restrict__ bs,
    const float* __restrict__ Wt, const float* __restrict__ bt,
    const float* __restrict__ W1, const float* __restrict__ a1s, const float* __restrict__ a1d,
    const float* __restrict__ W2, const float* __restrict__ a2s, const float* __restrict__ a2d,
    float* __restrict__ h1, float* __restrict__ h2,
    float* __restrict__ as1, float* __restrict__ ad1,
    float* __restrict__ as2, float* __restrict__ ad2) {
    __shared__ float Wl[128 * 132];
    __shared__ float Xl[128 * 33];
    const int tid = threadIdx.x;
    const int tc = tid & 31, tr = tid >> 5;
    const int half = blockIdx.y;
    const int row0 = blockIdx.x * 32;
    const float* xin = half ? xt : xs;
    const float* W0  = half ? Wt : Ws;
    const float* b0  = half ? bt : bs;

    // stage W0 + input tile (transposed: Xl[k][r])
    stage_w(Wl, W0, tid);
    for (int idx = tid; idx < 32 * 128; idx += 256) {
        int r = idx >> 7, k = idx & 127;
        int gr = row0 + r;
        Xl[k * 33 + r] = (gr < NS) ? xin[(size_t)gr * DD + k] : 0.f;
    }
    __syncthreads();

    float acc[16];
    // phase 1: x = xin @ W0.T + b0
    gemm_phase(Wl, Xl, tr, tc, acc);
    float bv[4];
#pragma unroll
    for (int c = 0; c < 4; c++) bv[c] = b0[tc * 4 + c];
#pragma unroll
    for (int rr = 0; rr < 4; rr++)
#pragma unroll
        for (int c = 0; c < 4; c++) acc[rr * 4 + c] += bv[c];
    __syncthreads();
    // write x back into Xl transposed; stage W1
#pragma unroll
    for (int rr = 0; rr < 4; rr++)
#pragma unroll
        for (int c = 0; c < 4; c++)
            Xl[(tc * 4 + c) * 33 + (tr * 4 + rr)] = acc[rr * 4 + c];
    stage_w(Wl, W1, tid);
    __syncthreads();

    // phase 2: h1 = x @ W1.T
    gemm_phase(Wl, Xl, tr, tc, acc);
    epilogue_store(acc, half, row0, tr, tc, a1s, a1d, h1, as1, ad1);
    __syncthreads();
    stage_w(Wl, W2, tid);
    __syncthreads();

    // phase 3: h2 = x @ W2.T
    gemm_phase(Wl, Xl, tr, tc, acc);
    epilogue_store(acc, half, row0, tr, tc, a2s, a2d, h2, as2, ad2);
}

// ---------------------------------------------------------------------------
// Edge enumeration. CONV==1: edges (src, dst+NS) ++ author ++ self-loops
// [NS,N). CONV==2: edges (dst+NS, src) ++ paper ++ self-loops [0,NS).
// ---------------------------------------------------------------------------
template <int CONV>
__device__ __forceinline__ void edge_sd(int e, const int* __restrict__ ei,
                                        const int* __restrict__ pei,
                                        const int* __restrict__ aei, int& s, int& d) {
    if (e < E0) {
        if (CONV == 1) { s = ei[e];        d = ei[E0 + e] + NS; }
        else           { s = ei[E0 + e] + NS; d = ei[e]; }
    } else if (e < 2 * E0) {
        const int k = e - E0;
        const int* o = (CONV == 1) ? aei : pei;
        s = o[k]; d = o[E0 + k];
    } else {
        const int k = e - 2 * E0;
        if (CONV == 1) { s = NS + k; d = NS + k; }
        else           { s = k;      d = k; }
    }
}

template <int CONV>
__global__ void k_edge_softmax(const int* __restrict__ ei, const int* __restrict__ pei,
                               const int* __restrict__ aei,
                               const float* __restrict__ as_, const float* __restrict__ ad_,
                               float* __restrict__ ee, float* __restrict__ denom) {
    const int e = blockIdx.x * 256 + threadIdx.x;
    if (e >= ETOT) return;
    int s, d;
    edge_sd<CONV>(e, ei, pei, aei, s, d);
    const bool inr = (CONV == 1) ? (d >= NS) : (d < NS);
    if (!inr) return;
    const int dl = (CONV == 1) ? d - NS : d;
    float v = as_[s] + ad_[d];
    v = v > 0.f ? v : 0.2f * v;
    const float x = __expf(v);
    ee[e] = x;
    unsafeAtomicAdd(&denom[dl], x);
}

template <int CONV>
__global__ void k_edge_scatter(const int* __restrict__ ei, const int* __restrict__ pei,
                               const int* __restrict__ aei,
                               const float* __restrict__ h, const float* __restrict__ ee,
                               const float* __restrict__ denom, float* __restrict__ outb) {
    const int e = blockIdx.x * 8 + (threadIdx.x >> 5);
    const int lane = threadIdx.x & 31;
    if (e >= ETOT) return;
    int s, d;
    edge_sd<CONV>(e, ei, pei, aei, s, d);
    const bool inr = (CONV == 1) ? (d >= NS) : (d < NS);
    if (!inr) return;
    const int dl = (CONV == 1) ? d - NS : d;
    const float alpha = ee[e] / (denom[dl] + 1e-16f);
    const float4 hv = ((const float4*)(h + (size_t)s * DD))[lane];
    float* o = outb + (size_t)dl * DD + lane * 4;
    unsafeAtomicAdd(o + 0, hv.x * alpha);
    unsafeAtomicAdd(o + 1, hv.y * alpha);
    unsafeAtomicAdd(o + 2, hv.z * alpha);
    unsafeAtomicAdd(o + 3, hv.w * alpha);
}

__global__ void k_relu(float* __restrict__ o, int n4) {
    const int i = blockIdx.x * blockDim.x + threadIdx.x;
    if (i < n4) {
        float4 v = ((float4*)o)[i];
        v.x = fmaxf(v.x, 0.f);
        v.y = fmaxf(v.y, 0.f);
        v.z = fmaxf(v.z, 0.f);
        v.w = fmaxf(v.w, 0.f);
        ((float4*)o)[i] = v;
    }
}

extern "C" void kernel_launch(void* const* d_in, const int* in_sizes, int n_in,
                              void* d_out, int out_size, void* d_ws, size_t ws_size,
                              hipStream_t stream) {
    const int* ei  = (const int*)d_in[0];
    const int* pei = (const int*)d_in[1];
    const int* aei = (const int*)d_in[2];
    const float* xs  = (const float*)d_in[3];
    const float* xt  = (const float*)d_in[4];
    const float* Ws  = (const float*)d_in[5];
    const float* bs  = (const float*)d_in[6];
    const float* Wt  = (const float*)d_in[7];
    const float* bt  = (const float*)d_in[8];
    const float* W1  = (const float*)d_in[9];
    const float* a1s = (const float*)d_in[10];
    const float* a1d = (const float*)d_in[11];
    const float* W2  = (const float*)d_in[12];
    const float* a2s = (const float*)d_in[13];
    const float* a2d = (const float*)d_in[14];
    float* ws  = (float*)d_ws;
    float* out = (float*)d_out;

    // zero d_out (scatter target) and the two denom arrays
    hipMemsetAsync(d_out, 0, (size_t)out_size * sizeof(float), stream);
    hipMemsetAsync(ws + OFF_DEN1, 0, 100000 * sizeof(float), stream);

    k_gemm<<<dim3(1563, 2), 256, 0, stream>>>(
        xs, xt, Ws, bs, Wt, bt, W1, a1s, a1d, W2, a2s, a2d,
        ws + OFF_H1, ws + OFF_H2, ws + OFF_AS1, ws + OFF_AD1, ws + OFF_AS2, ws + OFF_AD2);

    const int smx_blocks = (ETOT + 255) / 256;
    k_edge_softmax<1><<<smx_blocks, 256, 0, stream>>>(
        ei, pei, aei, ws + OFF_AS1, ws + OFF_AD1, ws + OFF_EE1, ws + OFF_DEN1);
    k_edge_softmax<2><<<smx_blocks, 256, 0, stream>>>(
        ei, pei, aei, ws + OFF_AS2, ws + OFF_AD2, ws + OFF_EE2, ws + OFF_DEN2);

    const int sc_blocks = ETOT / 8;  // 1,050,000 / 8 = 131,250 exactly
    // conv1 output -> rows [NS, N) -> second half of d_out
    k_edge_scatter<1><<<sc_blocks, 256, 0, stream>>>(
        ei, pei, aei, ws + OFF_H1, ws + OFF_EE1, ws + OFF_DEN1, out + (size_t)NS * DD);
    // conv2 output -> rows [0, NS) -> first half of d_out
    k_edge_scatter<2><<<sc_blocks, 256, 0, stream>>>(
        ei, pei, aei, ws + OFF_H2, ws + OFF_EE2, ws + OFF_DEN2, out);

    k_relu<<<(out_size / 4 + 255) / 256, 256, 0, stream>>>(out, out_size / 4);
}

// Round 2
// 873.739 us; speedup vs baseline: 3.7621x; 3.7621x over previous
//
#include <hip/hip_runtime.h>
#include <hip/hip_bf16.h>

// Problem constants
#define E0   500000
#define NS   50000
#define NT   50000
#define NND  100000
#define DD   128
#define ETOT (2*E0 + NS)   // per-conv edges incl. in-range self loops = 1,050,000
#define EMAX 1100000       // CSR capacity per conv

// workspace layout (in float/int units, 4B each; REC offsets 8B-aligned)
#define OFF_H1   0UL
#define OFF_H2   12800000UL
#define OFF_AS1  25600000UL
#define OFF_AD1  25700000UL
#define OFF_AS2  25800000UL
#define OFF_AD2  25900000UL
#define OFF_DEG1 26000000UL
#define OFF_DEG2 26050000UL
#define OFF_RP1  26100000UL   // 50001 ints
#define OFF_RP2  26151000UL
#define OFF_CUR1 26202000UL
#define OFF_CUR2 26252000UL
#define OFF_REC1 26302000UL   // EMAX float2 = 2.2M floats
#define OFF_REC2 28502000UL
// total 30,702,000 * 4B = 122.8 MB

// ---------------------------------------------------------------------------
// Fused dense kernel: x = xin@W0.T + b0 ; h1 = x@W1.T ; h2 = x@W2.T
// attention dots fused into epilogues.
// ---------------------------------------------------------------------------
__device__ __forceinline__ void stage_w(float* Wl, const float* __restrict__ W, int tid) {
    for (int idx = tid; idx < 128 * 128; idx += 256) {
        int j = idx >> 7, k = idx & 127;
        Wl[k * 132 + j] = W[idx];
    }
}

__device__ __forceinline__ void gemm_phase(const float* Wl, const float* Xl,
                                           int tr, int tc, float acc[16]) {
#pragma unroll
    for (int i = 0; i < 16; i++) acc[i] = 0.f;
#pragma unroll 8
    for (int k = 0; k < 128; k++) {
        const float4 w4 = *(const float4*)(Wl + k * 132 + tc * 4);
        const float x0 = Xl[k * 33 + tr * 4 + 0];
        const float x1 = Xl[k * 33 + tr * 4 + 1];
        const float x2 = Xl[k * 33 + tr * 4 + 2];
        const float x3 = Xl[k * 33 + tr * 4 + 3];
        acc[0]  += x0 * w4.x; acc[1]  += x0 * w4.y; acc[2]  += x0 * w4.z; acc[3]  += x0 * w4.w;
        acc[4]  += x1 * w4.x; acc[5]  += x1 * w4.y; acc[6]  += x1 * w4.z; acc[7]  += x1 * w4.w;
        acc[8]  += x2 * w4.x; acc[9]  += x2 * w4.y; acc[10] += x2 * w4.z; acc[11] += x2 * w4.w;
        acc[12] += x3 * w4.x; acc[13] += x3 * w4.y; acc[14] += x3 * w4.z; acc[15] += x3 * w4.w;
    }
}

__device__ __forceinline__ void epilogue_store(const float acc[16], int half, int row0,
                                               int tr, int tc,
                                               const float* __restrict__ av_s,
                                               const float* __restrict__ av_d,
                                               float* __restrict__ h,
                                               float* __restrict__ as_,
                                               float* __restrict__ ad_) {
    float a_sv[4], a_dv[4];
#pragma unroll
    for (int c = 0; c < 4; c++) { a_sv[c] = av_s[tc * 4 + c]; a_dv[c] = av_d[tc * 4 + c]; }
#pragma unroll
    for (int rr = 0; rr < 4; rr++) {
        const int gr = row0 + tr * 4 + rr;
        const bool ok = (gr < NS);
        const int node = half * NS + gr;
        if (ok) {
            *(float4*)(h + (size_t)node * DD + tc * 4) =
                make_float4(acc[rr * 4 + 0], acc[rr * 4 + 1], acc[rr * 4 + 2], acc[rr * 4 + 3]);
        }
        float ps = acc[rr * 4 + 0] * a_sv[0] + acc[rr * 4 + 1] * a_sv[1] +
                   acc[rr * 4 + 2] * a_sv[2] + acc[rr * 4 + 3] * a_sv[3];
        float pd = acc[rr * 4 + 0] * a_dv[0] + acc[rr * 4 + 1] * a_dv[1] +
                   acc[rr * 4 + 2] * a_dv[2] + acc[rr * 4 + 3] * a_dv[3];
#pragma unroll
        for (int m = 16; m; m >>= 1) { ps += __shfl_xor(ps, m); pd += __shfl_xor(pd, m); }
        if (ok && tc == 0) { as_[node] = ps; ad_[node] = pd; }
    }
}

__global__ __launch_bounds__(256, 1) void k_gemm(
    const float* __restrict__ xs, const float* __restrict__ xt,
    const float* __restrict__ Ws, const float* __restrict__ bs,
    const float* __restrict__ Wt, const float* __restrict__ bt,
    const float* __restrict__ W1, const float* __restrict__ a1s, const float* __restrict__ a1d,
    const float* __restrict__ W2, const float* __restrict__ a2s, const float* __restrict__ a2d,
    float* __restrict__ h1, float* __restrict__ h2,
    float* __restrict__ as1, float* __restrict__ ad1,
    float* __restrict__ as2, float* __restrict__ ad2) {
    __shared__ float Wl[128 * 132];
    __shared__ float Xl[128 * 33];
    const int tid = threadIdx.x;
    const int tc = tid & 31, tr = tid >> 5;
    const int half = blockIdx.y;
    const int row0 = blockIdx.x * 32;
    const float* xin = half ? xt : xs;
    const float* W0  = half ? Wt : Ws;
    const float* b0  = half ? bt : bs;

    stage_w(Wl, W0, tid);
    for (int idx = tid; idx < 32 * 128; idx += 256) {
        int r = idx >> 7, k = idx & 127;
        int gr = row0 + r;
        Xl[k * 33 + r] = (gr < NS) ? xin[(size_t)gr * DD + k] : 0.f;
    }
    __syncthreads();

    float acc[16];
    gemm_phase(Wl, Xl, tr, tc, acc);
    float bv[4];
#pragma unroll
    for (int c = 0; c < 4; c++) bv[c] = b0[tc * 4 + c];
#pragma unroll
    for (int rr = 0; rr < 4; rr++)
#pragma unroll
        for (int c = 0; c < 4; c++) acc[rr * 4 + c] += bv[c];
    __syncthreads();
#pragma unroll
    for (int rr = 0; rr < 4; rr++)
#pragma unroll
        for (int c = 0; c < 4; c++)
            Xl[(tc * 4 + c) * 33 + (tr * 4 + rr)] = acc[rr * 4 + c];
    stage_w(Wl, W1, tid);
    __syncthreads();

    gemm_phase(Wl, Xl, tr, tc, acc);
    epilogue_store(acc, half, row0, tr, tc, a1s, a1d, h1, as1, ad1);
    __syncthreads();
    stage_w(Wl, W2, tid);
    __syncthreads();

    gemm_phase(Wl, Xl, tr, tc, acc);
    epilogue_store(acc, half, row0, tr, tc, a2s, a2d, h2, as2, ad2);
}

// ---------------------------------------------------------------------------
// Edge enumeration. CONV==1: (src, dst+NS) ++ author ++ self-loops [NS,N).
// CONV==2: (dst+NS, src) ++ paper ++ self-loops [0,NS).
// ---------------------------------------------------------------------------
template <int CONV>
__device__ __forceinline__ void edge_sd(int e, const int* __restrict__ ei,
                                        const int* __restrict__ pei,
                                        const int* __restrict__ aei, int& s, int& d) {
    if (e < E0) {
        if (CONV == 1) { s = ei[e];           d = ei[E0 + e] + NS; }
        else           { s = ei[E0 + e] + NS; d = ei[e]; }
    } else if (e < 2 * E0) {
        const int k = e - E0;
        const int* o = (CONV == 1) ? aei : pei;
        s = o[k]; d = o[E0 + k];
    } else {
        const int k = e - 2 * E0;
        if (CONV == 1) { s = NS + k; d = NS + k; }
        else           { s = k;      d = k; }
    }
}

template <int CONV>
__device__ __forceinline__ bool in_range_dl(int d, int& dl) {
    if (CONV == 1) { dl = d - NS; return d >= NS; }
    else           { dl = d;      return d < NS; }
}

template <int CONV>
__global__ void k_count(const int* __restrict__ ei, const int* __restrict__ pei,
                        const int* __restrict__ aei, int* __restrict__ deg) {
    const int e = blockIdx.x * 256 + threadIdx.x;
    if (e >= ETOT) return;
    int s, d, dl;
    edge_sd<CONV>(e, ei, pei, aei, s, d);
    if (!in_range_dl<CONV>(d, dl)) return;
    atomicAdd(&deg[dl], 1);
}

// grid=2 blocks (one per conv), block=1024. Exclusive scan of 50000 degrees.
__global__ __launch_bounds__(1024) void k_scan(int* __restrict__ deg1, int* __restrict__ rp1,
                                               int* __restrict__ cur1,
                                               int* __restrict__ deg2, int* __restrict__ rp2,
                                               int* __restrict__ cur2) {
    __shared__ int ssum[1024];
    int* deg = blockIdx.x ? deg2 : deg1;
    int* rp  = blockIdx.x ? rp2  : rp1;
    int* cur = blockIdx.x ? cur2 : cur1;
    const int t = threadIdx.x;
    const int CH = 49;  // 1024*49 = 50176 >= 50000
    const int base = t * CH;
    int sum = 0;
    for (int i = 0; i < CH; i++) {
        int idx = base + i;
        if (idx < NS) sum += deg[idx];
    }
    ssum[t] = sum;
    __syncthreads();
    for (int off = 1; off < 1024; off <<= 1) {
        int v = (t >= off) ? ssum[t - off] : 0;
        __syncthreads();
        ssum[t] += v;
        __syncthreads();
    }
    int pre = t ? ssum[t - 1] : 0;
    for (int i = 0; i < CH; i++) {
        int idx = base + i;
        if (idx < NS) {
            rp[idx] = pre;
            cur[idx] = pre;
            pre += deg[idx];
        }
    }
    if (t == 1023) rp[NS] = ssum[1023];
}

template <int CONV>
__global__ void k_fill(const int* __restrict__ ei, const int* __restrict__ pei,
                       const int* __restrict__ aei,
                       const float* __restrict__ as_, const float* __restrict__ ad_,
                       int* __restrict__ cur, float2* __restrict__ rec) {
    const int e = blockIdx.x * 256 + threadIdx.x;
    if (e >= ETOT) return;
    int s, d, dl;
    edge_sd<CONV>(e, ei, pei, aei, s, d);
    if (!in_range_dl<CONV>(d, dl)) return;
    float v = as_[s] + ad_[d];
    v = v > 0.f ? v : 0.2f * v;
    const float ee = __expf(v);
    const int pos = atomicAdd(&cur[dl], 1);
    rec[pos] = make_float2(__int_as_float(s), ee);
}

// one wave64 per dst node; two half-waves process edges in parallel.
__global__ __launch_bounds__(256) void k_gather(const int* __restrict__ rp,
                                                const float2* __restrict__ rec,
                                                const float* __restrict__ h,
                                                float* __restrict__ outb) {
    const int node = blockIdx.x * 4 + (threadIdx.x >> 6);
    if (node >= NS) return;
    const int lane = threadIdx.x & 63;
    const int sub = lane >> 5, l32 = lane & 31;
    const int beg = rp[node], end = rp[node + 1];
    float4 acc = make_float4(0.f, 0.f, 0.f, 0.f);
    float eesum = 0.f;
    for (int e = beg + sub; e < end; e += 2) {
        const float2 r = rec[e];
        const int s = __float_as_int(r.x);
        const float ee = r.y;
        eesum += ee;
        const float4 hv = *(const float4*)(h + (size_t)s * DD + l32 * 4);
        acc.x += ee * hv.x;
        acc.y += ee * hv.y;
        acc.z += ee * hv.z;
        acc.w += ee * hv.w;
    }
    acc.x += __shfl_xor(acc.x, 32);
    acc.y += __shfl_xor(acc.y, 32);
    acc.z += __shfl_xor(acc.z, 32);
    acc.w += __shfl_xor(acc.w, 32);
    eesum += __shfl_xor(eesum, 32);
    if (sub == 0) {
        const float inv = 1.f / (eesum + 1e-16f);
        float4 o;
        o.x = fmaxf(acc.x * inv, 0.f);
        o.y = fmaxf(acc.y * inv, 0.f);
        o.z = fmaxf(acc.z * inv, 0.f);
        o.w = fmaxf(acc.w * inv, 0.f);
        *(float4*)(outb + (size_t)node * DD + l32 * 4) = o;
    }
}

extern "C" void kernel_launch(void* const* d_in, const int* in_sizes, int n_in,
                              void* d_out, int out_size, void* d_ws, size_t ws_size,
                              hipStream_t stream) {
    const int* ei  = (const int*)d_in[0];
    const int* pei = (const int*)d_in[1];
    const int* aei = (const int*)d_in[2];
    const float* xs  = (const float*)d_in[3];
    const float* xt  = (const float*)d_in[4];
    const float* Ws  = (const float*)d_in[5];
    const float* bs  = (const float*)d_in[6];
    const float* Wt  = (const float*)d_in[7];
    const float* bt  = (const float*)d_in[8];
    const float* W1  = (const float*)d_in[9];
    const float* a1s = (const float*)d_in[10];
    const float* a1d = (const float*)d_in[11];
    const float* W2  = (const float*)d_in[12];
    const float* a2s = (const float*)d_in[13];
    const float* a2d = (const float*)d_in[14];
    float* ws  = (float*)d_ws;
    float* out = (float*)d_out;

    int* deg1 = (int*)(ws + OFF_DEG1);
    int* deg2 = (int*)(ws + OFF_DEG2);
    int* rp1  = (int*)(ws + OFF_RP1);
    int* rp2  = (int*)(ws + OFF_RP2);
    int* cur1 = (int*)(ws + OFF_CUR1);
    int* cur2 = (int*)(ws + OFF_CUR2);
    float2* rec1 = (float2*)(ws + OFF_REC1);
    float2* rec2 = (float2*)(ws + OFF_REC2);

    // zero degree histograms (contiguous DEG1,DEG2)
    hipMemsetAsync(deg1, 0, 2 * NS * sizeof(int), stream);

    k_gemm<<<dim3(1563, 2), 256, 0, stream>>>(
        xs, xt, Ws, bs, Wt, bt, W1, a1s, a1d, W2, a2s, a2d,
        ws + OFF_H1, ws + OFF_H2, ws + OFF_AS1, ws + OFF_AD1, ws + OFF_AS2, ws + OFF_AD2);

    const int eb = (ETOT + 255) / 256;
    k_count<1><<<eb, 256, 0, stream>>>(ei, pei, aei, deg1);
    k_count<2><<<eb, 256, 0, stream>>>(ei, pei, aei, deg2);
    k_scan<<<2, 1024, 0, stream>>>(deg1, rp1, cur1, deg2, rp2, cur2);
    k_fill<1><<<eb, 256, 0, stream>>>(ei, pei, aei, ws + OFF_AS1, ws + OFF_AD1, cur1, rec1);
    k_fill<2><<<eb, 256, 0, stream>>>(ei, pei, aei, ws + OFF_AS2, ws + OFF_AD2, cur2, rec2);

    // conv1 output -> rows [NS, N) ; conv2 output -> rows [0, NS)
    k_gather<<<(NS + 3) / 4, 256, 0, stream>>>(rp1, rec1, ws + OFF_H1, out + (size_t)NS * DD);
    k_gather<<<(NS + 3) / 4, 256, 0, stream>>>(rp2, rec2, ws + OFF_H2, out);
}

// Round 3
// 525.833 us; speedup vs baseline: 6.2512x; 1.6616x over previous
//
#include <hip/hip_runtime.h>
#include <hip/hip_bf16.h>

// Problem constants
#define E0   500000
#define NS   50000
#define DD   128
#define ETOT (2*E0 + NS)   // per-conv edges incl. self loops = 1,050,000

// workspace layout (in 4B float units)
#define OFF_H1   0UL          // ushort[100000*128] = 6.4M floats
#define OFF_H2   6400000UL
#define OFF_AS1  12800000UL   // float[100000]
#define OFF_AD1  12900000UL
#define OFF_AS2  13000000UL
#define OFF_AD2  13100000UL
#define OFF_DEG1 13200000UL
#define OFF_DEG2 13250000UL
#define OFF_RP1  13300000UL   // 50001 ints
#define OFF_RP2  13351000UL
#define OFF_CUR1 13402000UL
#define OFF_CUR2 13452000UL
#define OFF_REC1 13502000UL   // float2[1100000] (byte off % 8 == 0)
#define OFF_REC2 15702000UL
// total ~17.9M floats = 71.6 MB

typedef __bf16 bf16x8 __attribute__((ext_vector_type(8)));
typedef float f32x4 __attribute__((ext_vector_type(4)));

__device__ __forceinline__ ushort f2bf(float f) {
    uint b = __float_as_uint(f);
    return (ushort)((b + 0x7FFFu + ((b >> 16) & 1u)) >> 16);
}
__device__ __forceinline__ float bf2f(ushort u) { return __uint_as_float(((uint)u) << 16); }
__device__ __forceinline__ uint pk2(float a, float b) {
    return (uint)f2bf(a) | ((uint)f2bf(b) << 16);
}

// ---------------------------------------------------------------------------
// Fused dense kernel (MFMA bf16): x = xin@W0.T + b0 ; h1 = x@W1.T ; h2 = x@W2.T
// 64 rows/block, 4 waves, each wave owns 16 rows. W/X tiles bf16 in LDS with
// XOR swizzle (byte ^= (row&7)<<4) -> conflict-free ds_read_b128 frag reads.
// ---------------------------------------------------------------------------
__device__ __forceinline__ void stage_w_bf16(ushort* Wl, const float* __restrict__ W, int tid) {
#pragma unroll
    for (int i = 0; i < 8; i++) {
        const int idx = i * 256 + tid;          // 2048 chunks of 16B
        const int row = idx >> 4, ch = idx & 15;
        const float4 f0 = *(const float4*)(W + row * DD + ch * 8);
        const float4 f1 = *(const float4*)(W + row * DD + ch * 8 + 4);
        uint4 v = make_uint4(pk2(f0.x, f0.y), pk2(f0.z, f0.w), pk2(f1.x, f1.y), pk2(f1.z, f1.w));
        *(uint4*)((char*)Wl + ((row * 256 + ch * 16) ^ ((row & 7) << 4))) = v;
    }
}

__device__ __forceinline__ void stage_x(ushort* Xl, const float* __restrict__ xin,
                                        int row0, int tid) {
#pragma unroll
    for (int i = 0; i < 4; i++) {
        const int idx = i * 256 + tid;          // 1024 chunks of 16B
        const int r = idx >> 4, ch = idx & 15;
        const int gr = row0 + r;
        float4 f0 = make_float4(0.f, 0.f, 0.f, 0.f), f1 = f0;
        if (gr < NS) {
            f0 = *(const float4*)(xin + (size_t)gr * DD + ch * 8);
            f1 = *(const float4*)(xin + (size_t)gr * DD + ch * 8 + 4);
        }
        uint4 v = make_uint4(pk2(f0.x, f0.y), pk2(f0.z, f0.w), pk2(f1.x, f1.y), pk2(f1.z, f1.w));
        *(uint4*)((char*)Xl + ((r * 256 + ch * 16) ^ ((r & 7) << 4))) = v;
    }
}

__device__ __forceinline__ void mfma_phase(const ushort* Wl, const ushort* Xl,
                                           int wrow, int lane, f32x4 acc[8]) {
    const int l15 = lane & 15, q = lane >> 4;
    bf16x8 a[4];
#pragma unroll
    for (int ks = 0; ks < 4; ks++) {
        const int row = wrow + l15;
        const int byte = (row * 256 + (ks * 32 + q * 8) * 2) ^ ((row & 7) << 4);
        a[ks] = *(const bf16x8*)((const char*)Xl + byte);
    }
#pragma unroll
    for (int nt = 0; nt < 8; nt++) {
        const int n = nt * 16 + l15;
#pragma unroll
        for (int ks = 0; ks < 4; ks++) {
            const int byte = (n * 256 + (ks * 32 + q * 8) * 2) ^ ((n & 7) << 4);
            bf16x8 b = *(const bf16x8*)((const char*)Wl + byte);
            acc[nt] = __builtin_amdgcn_mfma_f32_16x16x32_bf16(a[ks], b, acc[nt], 0, 0, 0);
        }
    }
}

__device__ __forceinline__ void epi23(const f32x4 acc[8], int half, int row0, int wrow,
                                      int lane, const float* __restrict__ avs,
                                      const float* __restrict__ avd,
                                      ushort* __restrict__ h,
                                      float* __restrict__ as_, float* __restrict__ ad_) {
    const int l15 = lane & 15, q = lane >> 4;
    float vs[8], vd[8];
#pragma unroll
    for (int nt = 0; nt < 8; nt++) { vs[nt] = avs[nt * 16 + l15]; vd[nt] = avd[nt * 16 + l15]; }
#pragma unroll
    for (int r = 0; r < 4; r++) {
        const int gr = row0 + wrow + q * 4 + r;
        const bool ok = gr < NS;
        const size_t node = (size_t)(half * NS + gr);
        float ps = 0.f, pd = 0.f;
#pragma unroll
        for (int nt = 0; nt < 8; nt++) {
            const float v = acc[nt][r];
            ps += v * vs[nt];
            pd += v * vd[nt];
            if (ok) h[node * DD + nt * 16 + l15] = f2bf(v);
        }
#pragma unroll
        for (int m = 8; m; m >>= 1) { ps += __shfl_xor(ps, m); pd += __shfl_xor(pd, m); }
        if (ok && l15 == 0) { as_[node] = ps; ad_[node] = pd; }
    }
}

__global__ __launch_bounds__(256) void k_gemm(
    const float* __restrict__ xs, const float* __restrict__ xt,
    const float* __restrict__ Ws, const float* __restrict__ bs,
    const float* __restrict__ Wt, const float* __restrict__ bt,
    const float* __restrict__ W1, const float* __restrict__ a1s, const float* __restrict__ a1d,
    const float* __restrict__ W2, const float* __restrict__ a2s, const float* __restrict__ a2d,
    ushort* __restrict__ h1, ushort* __restrict__ h2,
    float* __restrict__ as1, float* __restrict__ ad1,
    float* __restrict__ as2, float* __restrict__ ad2) {
    __shared__ __align__(16) ushort Wl[128 * 128];  // 32 KB
    __shared__ __align__(16) ushort Xl[64 * 128];   // 16 KB
    const int tid = threadIdx.x;
    const int lane = tid & 63, wv = tid >> 6, wrow = wv * 16;
    const int l15 = lane & 15, q = lane >> 4;
    const int half = blockIdx.y;
    const int row0 = blockIdx.x * 64;
    const float* xin = half ? xt : xs;
    const float* W0  = half ? Wt : Ws;
    const float* b0  = half ? bt : bs;

    stage_w_bf16(Wl, W0, tid);
    stage_x(Xl, xin, row0, tid);
    __syncthreads();

    f32x4 acc[8];
#pragma unroll
    for (int nt = 0; nt < 8; nt++) acc[nt] = 0.f;
    mfma_phase(Wl, Xl, wrow, lane, acc);

    // bias add + write x (bf16, swizzled) back into the wave's own 16 rows of Xl
#pragma unroll
    for (int nt = 0; nt < 8; nt++) {
        const float bvv = b0[nt * 16 + l15];
#pragma unroll
        for (int r = 0; r < 4; r++) {
            const int row = wrow + q * 4 + r;
            const int byte = (row * 256 + (nt * 16 + l15) * 2) ^ ((row & 7) << 4);
            *(ushort*)((char*)Xl + byte) = f2bf(acc[nt][r] + bvv);
        }
    }
    __syncthreads();
    stage_w_bf16(Wl, W1, tid);
    __syncthreads();

#pragma unroll
    for (int nt = 0; nt < 8; nt++) acc[nt] = 0.f;
    mfma_phase(Wl, Xl, wrow, lane, acc);
    epi23(acc, half, row0, wrow, lane, a1s, a1d, h1, as1, ad1);

    __syncthreads();
    stage_w_bf16(Wl, W2, tid);
    __syncthreads();

#pragma unroll
    for (int nt = 0; nt < 8; nt++) acc[nt] = 0.f;
    mfma_phase(Wl, Xl, wrow, lane, acc);
    epi23(acc, half, row0, wrow, lane, a2s, a2d, h2, as2, ad2);
}

// ---------------------------------------------------------------------------
// Edge pipeline: count -> scan -> fill (CSR) -> gather. Both convs fused.
// conv1: (src, dst+NS) ++ author ++ loops[NS,N) ; out rows [NS,N)
// conv2: (dst+NS, src) ++ paper  ++ loops[0,NS) ; out rows [0,NS)
// ---------------------------------------------------------------------------
__global__ void k_count_both(const int* __restrict__ ei, const int* __restrict__ pei,
                             const int* __restrict__ aei,
                             int* __restrict__ deg1, int* __restrict__ deg2) {
    const int e = blockIdx.x * 256 + threadIdx.x;
    if (e >= ETOT) return;
    if (e < E0) {
        const int a = ei[e], b = ei[E0 + e];
        atomicAdd(&deg1[b], 1);   // conv1 dst = b+NS
        atomicAdd(&deg2[a], 1);   // conv2 dst = a
    } else if (e < 2 * E0) {
        const int k = e - E0;
        const int d1 = aei[E0 + k];
        if (d1 >= NS) atomicAdd(&deg1[d1 - NS], 1);
        const int d2 = pei[E0 + k];
        if (d2 < NS) atomicAdd(&deg2[d2], 1);
    } else {
        const int k = e - 2 * E0;
        atomicAdd(&deg1[k], 1);
        atomicAdd(&deg2[k], 1);
    }
}

__global__ __launch_bounds__(1024) void k_scan(int* __restrict__ deg1, int* __restrict__ rp1,
                                               int* __restrict__ cur1,
                                               int* __restrict__ deg2, int* __restrict__ rp2,
                                               int* __restrict__ cur2) {
    __shared__ int ssum[1024];
    int* deg = blockIdx.x ? deg2 : deg1;
    int* rp  = blockIdx.x ? rp2  : rp1;
    int* cur = blockIdx.x ? cur2 : cur1;
    const int t = threadIdx.x;
    const int CH = 49;  // 1024*49 >= 50000
    const int base = t * CH;
    int sum = 0;
    for (int i = 0; i < CH; i++) {
        int idx = base + i;
        if (idx < NS) sum += deg[idx];
    }
    ssum[t] = sum;
    __syncthreads();
    for (int off = 1; off < 1024; off <<= 1) {
        int v = (t >= off) ? ssum[t - off] : 0;
        __syncthreads();
        ssum[t] += v;
        __syncthreads();
    }
    int pre = t ? ssum[t - 1] : 0;
    for (int i = 0; i < CH; i++) {
        int idx = base + i;
        if (idx < NS) {
            rp[idx] = pre;
            cur[idx] = pre;
            pre += deg[idx];
        }
    }
    if (t == 1023) rp[NS] = ssum[1023];
}

__device__ __forceinline__ float att_ee(float as_v, float ad_v) {
    float v = as_v + ad_v;
    v = v > 0.f ? v : 0.2f * v;
    return __expf(v);
}

__global__ void k_fill_both(const int* __restrict__ ei, const int* __restrict__ pei,
                            const int* __restrict__ aei,
                            const float* __restrict__ as1, const float* __restrict__ ad1,
                            const float* __restrict__ as2, const float* __restrict__ ad2,
                            int* __restrict__ cur1, float2* __restrict__ rec1,
                            int* __restrict__ cur2, float2* __restrict__ rec2) {
    const int e = blockIdx.x * 256 + threadIdx.x;
    if (e >= ETOT) return;
    if (e < E0) {
        const int a = ei[e], b = ei[E0 + e];
        {   // conv1: s=a, d=b+NS
            const float ee = att_ee(as1[a], ad1[b + NS]);
            const int pos = atomicAdd(&cur1[b], 1);
            rec1[pos] = make_float2(__int_as_float(a), ee);
        }
        {   // conv2: s=b+NS, d=a
            const float ee = att_ee(as2[b + NS], ad2[a]);
            const int pos = atomicAdd(&cur2[a], 1);
            rec2[pos] = make_float2(__int_as_float(b + NS), ee);
        }
    } else if (e < 2 * E0) {
        const int k = e - E0;
        const int s1 = aei[k], d1 = aei[E0 + k];
        if (d1 >= NS) {
            const float ee = att_ee(as1[s1], ad1[d1]);
            const int pos = atomicAdd(&cur1[d1 - NS], 1);
            rec1[pos] = make_float2(__int_as_float(s1), ee);
        }
        const int s2 = pei[k], d2 = pei[E0 + k];
        if (d2 < NS) {
            const float ee = att_ee(as2[s2], ad2[d2]);
            const int pos = atomicAdd(&cur2[d2], 1);
            rec2[pos] = make_float2(__int_as_float(s2), ee);
        }
    } else {
        const int k = e - 2 * E0;
        {
            const float ee = att_ee(as1[NS + k], ad1[NS + k]);
            const int pos = atomicAdd(&cur1[k], 1);
            rec1[pos] = make_float2(__int_as_float(NS + k), ee);
        }
        {
            const float ee = att_ee(as2[k], ad2[k]);
            const int pos = atomicAdd(&cur2[k], 1);
            rec2[pos] = make_float2(__int_as_float(k), ee);
        }
    }
}

// one wave64 per dst node; two 32-lane halves process edges in parallel.
__global__ __launch_bounds__(256) void k_gather(
    const int* __restrict__ rp1, const float2* __restrict__ rec1, const ushort* __restrict__ h1,
    const int* __restrict__ rp2, const float2* __restrict__ rec2, const ushort* __restrict__ h2,
    float* __restrict__ out) {
    const int conv = blockIdx.y;
    const int* rp = conv ? rp2 : rp1;
    const float2* rec = conv ? rec2 : rec1;
    const ushort* h = conv ? h2 : h1;
    float* outb = conv ? out : out + (size_t)NS * DD;  // conv1 -> rows [NS,N)
    const int node = blockIdx.x * 4 + (threadIdx.x >> 6);
    if (node >= NS) return;
    const int lane = threadIdx.x & 63, sub = lane >> 5, l32 = lane & 31;
    const int beg = rp[node], end = rp[node + 1];
    float4 acc = make_float4(0.f, 0.f, 0.f, 0.f);
    float es = 0.f;
    for (int e = beg + sub; e < end; e += 2) {
        const float2 r = rec[e];
        const int s = __float_as_int(r.x);
        const float ee = r.y;
        es += ee;
        const ushort4 hv = *(const ushort4*)(h + (size_t)s * DD + l32 * 4);
        acc.x += ee * bf2f(hv.x);
        acc.y += ee * bf2f(hv.y);
        acc.z += ee * bf2f(hv.z);
        acc.w += ee * bf2f(hv.w);
    }
    acc.x += __shfl_xor(acc.x, 32);
    acc.y += __shfl_xor(acc.y, 32);
    acc.z += __shfl_xor(acc.z, 32);
    acc.w += __shfl_xor(acc.w, 32);
    es += __shfl_xor(es, 32);
    if (sub == 0) {
        const float inv = 1.f / (es + 1e-16f);
        float4 o;
        o.x = fmaxf(acc.x * inv, 0.f);
        o.y = fmaxf(acc.y * inv, 0.f);
        o.z = fmaxf(acc.z * inv, 0.f);
        o.w = fmaxf(acc.w * inv, 0.f);
        *(float4*)(outb + (size_t)node * DD + l32 * 4) = o;
    }
}

extern "C" void kernel_launch(void* const* d_in, const int* in_sizes, int n_in,
                              void* d_out, int out_size, void* d_ws, size_t ws_size,
                              hipStream_t stream) {
    const int* ei  = (const int*)d_in[0];
    const int* pei = (const int*)d_in[1];
    const int* aei = (const int*)d_in[2];
    const float* xs  = (const float*)d_in[3];
    const float* xt  = (const float*)d_in[4];
    const float* Ws  = (const float*)d_in[5];
    const float* bs  = (const float*)d_in[6];
    const float* Wt  = (const float*)d_in[7];
    const float* bt  = (const float*)d_in[8];
    const float* W1  = (const float*)d_in[9];
    const float* a1s = (const float*)d_in[10];
    const float* a1d = (const float*)d_in[11];
    const float* W2  = (const float*)d_in[12];
    const float* a2s = (const float*)d_in[13];
    const float* a2d = (const float*)d_in[14];
    float* ws  = (float*)d_ws;
    float* out = (float*)d_out;

    ushort* h1 = (ushort*)(ws + OFF_H1);
    ushort* h2 = (ushort*)(ws + OFF_H2);
    int* deg1 = (int*)(ws + OFF_DEG1);
    int* deg2 = (int*)(ws + OFF_DEG2);
    int* rp1  = (int*)(ws + OFF_RP1);
    int* rp2  = (int*)(ws + OFF_RP2);
    int* cur1 = (int*)(ws + OFF_CUR1);
    int* cur2 = (int*)(ws + OFF_CUR2);
    float2* rec1 = (float2*)(ws + OFF_REC1);
    float2* rec2 = (float2*)(ws + OFF_REC2);

    hipMemsetAsync(deg1, 0, 2 * NS * sizeof(int), stream);  // DEG1,DEG2 contiguous

    k_gemm<<<dim3((NS + 63) / 64, 2), 256, 0, stream>>>(
        xs, xt, Ws, bs, Wt, bt, W1, a1s, a1d, W2, a2s, a2d,
        h1, h2, ws + OFF_AS1, ws + OFF_AD1, ws + OFF_AS2, ws + OFF_AD2);

    const int eb = (ETOT + 255) / 256;
    k_count_both<<<eb, 256, 0, stream>>>(ei, pei, aei, deg1, deg2);
    k_scan<<<2, 1024, 0, stream>>>(deg1, rp1, cur1, deg2, rp2, cur2);
    k_fill_both<<<eb, 256, 0, stream>>>(ei, pei, aei,
                                        ws + OFF_AS1, ws + OFF_AD1, ws + OFF_AS2, ws + OFF_AD2,
                                        cur1, rec1, cur2, rec2);
    k_gather<<<dim3(NS / 4, 2), 256, 0, stream>>>(rp1, rec1, h1, rp2, rec2, h2, out);
}

// Round 4
// 405.819 us; speedup vs baseline: 8.0998x; 1.2957x over previous
//
#include <hip/hip_runtime.h>
#include <hip/hip_bf16.h>

// Problem constants
#define E0   500000
#define NS   50000
#define DD   128
#define ETOT (2*E0 + NS)   // per-conv edges incl. self loops = 1,050,000

// workspace layout (in 4B float units)
#define OFF_H1   0UL          // ushort[100000*128] = 6.4M floats
#define OFF_H2   6400000UL
#define OFF_AS1  12800000UL   // float[100000]
#define OFF_AD1  12900000UL
#define OFF_AS2  13000000UL
#define OFF_AD2  13100000UL
#define OFF_DEG1 13200000UL
#define OFF_DEG2 13250000UL
#define OFF_RP1  13300000UL   // 50001 ints
#define OFF_RP2  13351000UL
#define OFF_CUR1 13402000UL
#define OFF_CUR2 13452000UL
#define OFF_PS   13502000UL   // 128 ints (block partial sums, stride 64/conv)
#define OFF_PREF 13502128UL   // 128 ints (block prefixes)
#define OFF_REC1 13502256UL   // float2[1100000]
#define OFF_REC2 15702256UL
// total ~17.9M floats = 71.6 MB

typedef __bf16 bf16x8 __attribute__((ext_vector_type(8)));
typedef float f32x4 __attribute__((ext_vector_type(4)));

__device__ __forceinline__ ushort f2bf(float f) {
    uint b = __float_as_uint(f);
    return (ushort)((b + 0x7FFFu + ((b >> 16) & 1u)) >> 16);
}
__device__ __forceinline__ float bf2f(ushort u) { return __uint_as_float(((uint)u) << 16); }
__device__ __forceinline__ uint pk2(float a, float b) {
    return (uint)f2bf(a) | ((uint)f2bf(b) << 16);
}

// ---------------------------------------------------------------------------
// Fused dense kernel (MFMA bf16): x = xin@W0.T + b0 ; h1 = x@W1.T ; h2 = x@W2.T
// ---------------------------------------------------------------------------
__device__ __forceinline__ void stage_w_bf16(ushort* Wl, const float* __restrict__ W, int tid) {
#pragma unroll
    for (int i = 0; i < 8; i++) {
        const int idx = i * 256 + tid;          // 2048 chunks of 16B
        const int row = idx >> 4, ch = idx & 15;
        const float4 f0 = *(const float4*)(W + row * DD + ch * 8);
        const float4 f1 = *(const float4*)(W + row * DD + ch * 8 + 4);
        uint4 v = make_uint4(pk2(f0.x, f0.y), pk2(f0.z, f0.w), pk2(f1.x, f1.y), pk2(f1.z, f1.w));
        *(uint4*)((char*)Wl + ((row * 256 + ch * 16) ^ ((row & 7) << 4))) = v;
    }
}

__device__ __forceinline__ void stage_x(ushort* Xl, const float* __restrict__ xin,
                                        int row0, int tid) {
#pragma unroll
    for (int i = 0; i < 4; i++) {
        const int idx = i * 256 + tid;          // 1024 chunks of 16B
        const int r = idx >> 4, ch = idx & 15;
        const int gr = row0 + r;
        float4 f0 = make_float4(0.f, 0.f, 0.f, 0.f), f1 = f0;
        if (gr < NS) {
            f0 = *(const float4*)(xin + (size_t)gr * DD + ch * 8);
            f1 = *(const float4*)(xin + (size_t)gr * DD + ch * 8 + 4);
        }
        uint4 v = make_uint4(pk2(f0.x, f0.y), pk2(f0.z, f0.w), pk2(f1.x, f1.y), pk2(f1.z, f1.w));
        *(uint4*)((char*)Xl + ((r * 256 + ch * 16) ^ ((r & 7) << 4))) = v;
    }
}

__device__ __forceinline__ void mfma_phase(const ushort* Wl, const ushort* Xl,
                                           int wrow, int lane, f32x4 acc[8]) {
    const int l15 = lane & 15, q = lane >> 4;
    bf16x8 a[4];
#pragma unroll
    for (int ks = 0; ks < 4; ks++) {
        const int row = wrow + l15;
        const int byte = (row * 256 + (ks * 32 + q * 8) * 2) ^ ((row & 7) << 4);
        a[ks] = *(const bf16x8*)((const char*)Xl + byte);
    }
#pragma unroll
    for (int nt = 0; nt < 8; nt++) {
        const int n = nt * 16 + l15;
#pragma unroll
        for (int ks = 0; ks < 4; ks++) {
            const int byte = (n * 256 + (ks * 32 + q * 8) * 2) ^ ((n & 7) << 4);
            bf16x8 b = *(const bf16x8*)((const char*)Wl + byte);
            acc[nt] = __builtin_amdgcn_mfma_f32_16x16x32_bf16(a[ks], b, acc[nt], 0, 0, 0);
        }
    }
}

__device__ __forceinline__ void epi23(const f32x4 acc[8], int half, int row0, int wrow,
                                      int lane, const float* __restrict__ avs,
                                      const float* __restrict__ avd,
                                      ushort* __restrict__ h,
                                      float* __restrict__ as_, float* __restrict__ ad_) {
    const int l15 = lane & 15, q = lane >> 4;
    float vs[8], vd[8];
#pragma unroll
    for (int nt = 0; nt < 8; nt++) { vs[nt] = avs[nt * 16 + l15]; vd[nt] = avd[nt * 16 + l15]; }
#pragma unroll
    for (int r = 0; r < 4; r++) {
        const int gr = row0 + wrow + q * 4 + r;
        const bool ok = gr < NS;
        const size_t node = (size_t)(half * NS + gr);
        float ps = 0.f, pd = 0.f;
#pragma unroll
        for (int nt = 0; nt < 8; nt++) {
            const float v = acc[nt][r];
            ps += v * vs[nt];
            pd += v * vd[nt];
            if (ok) h[node * DD + nt * 16 + l15] = f2bf(v);
        }
#pragma unroll
        for (int m = 8; m; m >>= 1) { ps += __shfl_xor(ps, m); pd += __shfl_xor(pd, m); }
        if (ok && l15 == 0) { as_[node] = ps; ad_[node] = pd; }
    }
}

__global__ __launch_bounds__(256) void k_gemm(
    const float* __restrict__ xs, const float* __restrict__ xt,
    const float* __restrict__ Ws, const float* __restrict__ bs,
    const float* __restrict__ Wt, const float* __restrict__ bt,
    const float* __restrict__ W1, const float* __restrict__ a1s, const float* __restrict__ a1d,
    const float* __restrict__ W2, const float* __restrict__ a2s, const float* __restrict__ a2d,
    ushort* __restrict__ h1, ushort* __restrict__ h2,
    float* __restrict__ as1, float* __restrict__ ad1,
    float* __restrict__ as2, float* __restrict__ ad2) {
    __shared__ __align__(16) ushort Wl[128 * 128];  // 32 KB
    __shared__ __align__(16) ushort Xl[64 * 128];   // 16 KB
    const int tid = threadIdx.x;
    const int lane = tid & 63, wv = tid >> 6, wrow = wv * 16;
    const int l15 = lane & 15, q = lane >> 4;
    const int half = blockIdx.y;
    const int row0 = blockIdx.x * 64;
    const float* xin = half ? xt : xs;
    const float* W0  = half ? Wt : Ws;
    const float* b0  = half ? bt : bs;

    stage_w_bf16(Wl, W0, tid);
    stage_x(Xl, xin, row0, tid);
    __syncthreads();

    f32x4 acc[8];
#pragma unroll
    for (int nt = 0; nt < 8; nt++) acc[nt] = 0.f;
    mfma_phase(Wl, Xl, wrow, lane, acc);

#pragma unroll
    for (int nt = 0; nt < 8; nt++) {
        const float bvv = b0[nt * 16 + l15];
#pragma unroll
        for (int r = 0; r < 4; r++) {
            const int row = wrow + q * 4 + r;
            const int byte = (row * 256 + (nt * 16 + l15) * 2) ^ ((row & 7) << 4);
            *(ushort*)((char*)Xl + byte) = f2bf(acc[nt][r] + bvv);
        }
    }
    __syncthreads();
    stage_w_bf16(Wl, W1, tid);
    __syncthreads();

#pragma unroll
    for (int nt = 0; nt < 8; nt++) acc[nt] = 0.f;
    mfma_phase(Wl, Xl, wrow, lane, acc);
    epi23(acc, half, row0, wrow, lane, a1s, a1d, h1, as1, ad1);

    __syncthreads();
    stage_w_bf16(Wl, W2, tid);
    __syncthreads();

#pragma unroll
    for (int nt = 0; nt < 8; nt++) acc[nt] = 0.f;
    mfma_phase(Wl, Xl, wrow, lane, acc);
    epi23(acc, half, row0, wrow, lane, a2s, a2d, h2, as2, ad2);
}

// ---------------------------------------------------------------------------
// Edge pipeline: count -> scan(3 stages) -> fill (CSR) -> gather.
// conv1: (src, dst+NS) ++ author ++ loops[NS,N) ; out rows [NS,N)
// conv2: (dst+NS, src) ++ paper  ++ loops[0,NS) ; out rows [0,NS)
// ---------------------------------------------------------------------------
__global__ void k_count_both(const int* __restrict__ ei, const int* __restrict__ pei,
                             const int* __restrict__ aei,
                             int* __restrict__ deg1, int* __restrict__ deg2) {
    const int e = blockIdx.x * 256 + threadIdx.x;
    if (e >= ETOT) return;
    if (e < E0) {
        const int a = ei[e], b = ei[E0 + e];
        atomicAdd(&deg1[b], 1);
        atomicAdd(&deg2[a], 1);
    } else if (e < 2 * E0) {
        const int k = e - E0;
        const int d1 = aei[E0 + k];
        if (d1 >= NS) atomicAdd(&deg1[d1 - NS], 1);
        const int d2 = pei[E0 + k];
        if (d2 < NS) atomicAdd(&deg2[d2], 1);
    } else {
        const int k = e - 2 * E0;
        atomicAdd(&deg1[k], 1);
        atomicAdd(&deg2[k], 1);
    }
}

__device__ __forceinline__ int wave_incl_scan(int x, int lane) {
#pragma unroll
    for (int off = 1; off < 64; off <<= 1) {
        const int v = __shfl_up(x, off);
        if (lane >= off) x += v;
    }
    return x;
}

__device__ __forceinline__ int4 load_deg4(const int* __restrict__ d, int idx) {
    if (idx + 3 < NS) return *(const int4*)(d + idx);
    int4 v = make_int4(0, 0, 0, 0);
    if (idx + 0 < NS) v.x = d[idx + 0];
    if (idx + 1 < NS) v.y = d[idx + 1];
    if (idx + 2 < NS) v.z = d[idx + 2];
    if (idx + 3 < NS) v.w = d[idx + 3];
    return v;
}

// grid (49,2) x 256: per-block sum of 1024 degrees
__global__ __launch_bounds__(256) void k_scan1(const int* __restrict__ deg,
                                               int* __restrict__ psum) {
    const int conv = blockIdx.y, blk = blockIdx.x, t = threadIdx.x;
    const int* d = deg + conv * NS;
    const int4 v = load_deg4(d, blk * 1024 + t * 4);
    int s = v.x + v.y + v.z + v.w;
#pragma unroll
    for (int m = 32; m; m >>= 1) s += __shfl_xor(s, m);
    __shared__ int wsum[4];
    const int lane = t & 63, wv = t >> 6;
    if (lane == 0) wsum[wv] = s;
    __syncthreads();
    if (t == 0) psum[conv * 64 + blk] = wsum[0] + wsum[1] + wsum[2] + wsum[3];
}

// 1 block, 128 threads: exclusive scan of 49 partials per conv (wave each)
__global__ __launch_bounds__(128) void k_scan2(const int* __restrict__ psum,
                                               int* __restrict__ pref) {
    const int t = threadIdx.x;
    const int w = t >> 6, lane = t & 63;
    const int x = (lane < 49) ? psum[w * 64 + lane] : 0;
    const int incl = wave_incl_scan(x, lane);
    if (lane < 49) pref[w * 64 + lane] = incl - x;
}

// grid (49,2) x 256: intra-block exclusive scan + block prefix -> rp, cur
__global__ __launch_bounds__(256) void k_scan3(const int* __restrict__ deg,
                                               const int* __restrict__ pref,
                                               int* __restrict__ rp1, int* __restrict__ cur1,
                                               int* __restrict__ rp2, int* __restrict__ cur2) {
    const int conv = blockIdx.y, blk = blockIdx.x, t = threadIdx.x;
    const int* d = deg + conv * NS;
    int* rp  = conv ? rp2  : rp1;
    int* cur = conv ? cur2 : cur1;
    const int idx = blk * 1024 + t * 4;
    const int4 v = load_deg4(d, idx);
    const int tsum = v.x + v.y + v.z + v.w;
    const int lane = t & 63, wv = t >> 6;
    const int incl = wave_incl_scan(tsum, lane);
    __shared__ int wsum[4];
    if (lane == 63) wsum[wv] = incl;
    __syncthreads();
    int woff = 0;
#pragma unroll
    for (int i = 0; i < 4; i++) woff += (i < wv) ? wsum[i] : 0;
    int ex = pref[conv * 64 + blk] + woff + (incl - tsum);
    if (idx + 0 < NS) { rp[idx + 0] = ex; cur[idx + 0] = ex; } ex += v.x;
    if (idx + 1 < NS) { rp[idx + 1] = ex; cur[idx + 1] = ex; } ex += v.y;
    if (idx + 2 < NS) { rp[idx + 2] = ex; cur[idx + 2] = ex; } ex += v.z;
    if (idx + 3 < NS) { rp[idx + 3] = ex; cur[idx + 3] = ex; } ex += v.w;
    if (blk == 48 && t == 0)
        rp[NS] = pref[conv * 64 + 48] + wsum[0] + wsum[1] + wsum[2] + wsum[3];
}

__device__ __forceinline__ float att_ee(float as_v, float ad_v) {
    float v = as_v + ad_v;
    v = v > 0.f ? v : 0.2f * v;
    return __expf(v);
}

__global__ void k_fill_both(const int* __restrict__ ei, const int* __restrict__ pei,
                            const int* __restrict__ aei,
                            const float* __restrict__ as1, const float* __restrict__ ad1,
                            const float* __restrict__ as2, const float* __restrict__ ad2,
                            int* __restrict__ cur1, float2* __restrict__ rec1,
                            int* __restrict__ cur2, float2* __restrict__ rec2) {
    const int e = blockIdx.x * 256 + threadIdx.x;
    if (e >= ETOT) return;
    if (e < E0) {
        const int a = ei[e], b = ei[E0 + e];
        {
            const float ee = att_ee(as1[a], ad1[b + NS]);
            const int pos = atomicAdd(&cur1[b], 1);
            rec1[pos] = make_float2(__int_as_float(a), ee);
        }
        {
            const float ee = att_ee(as2[b + NS], ad2[a]);
            const int pos = atomicAdd(&cur2[a], 1);
            rec2[pos] = make_float2(__int_as_float(b + NS), ee);
        }
    } else if (e < 2 * E0) {
        const int k = e - E0;
        const int s1 = aei[k], d1 = aei[E0 + k];
        if (d1 >= NS) {
            const float ee = att_ee(as1[s1], ad1[d1]);
            const int pos = atomicAdd(&cur1[d1 - NS], 1);
            rec1[pos] = make_float2(__int_as_float(s1), ee);
        }
        const int s2 = pei[k], d2 = pei[E0 + k];
        if (d2 < NS) {
            const float ee = att_ee(as2[s2], ad2[d2]);
            const int pos = atomicAdd(&cur2[d2], 1);
            rec2[pos] = make_float2(__int_as_float(s2), ee);
        }
    } else {
        const int k = e - 2 * E0;
        {
            const float ee = att_ee(as1[NS + k], ad1[NS + k]);
            const int pos = atomicAdd(&cur1[k], 1);
            rec1[pos] = make_float2(__int_as_float(NS + k), ee);
        }
        {
            const float ee = att_ee(as2[k], ad2[k]);
            const int pos = atomicAdd(&cur2[k], 1);
            rec2[pos] = make_float2(__int_as_float(k), ee);
        }
    }
}

// one wave64 per dst node; two 32-lane halves process edges in parallel.
__global__ __launch_bounds__(256) void k_gather(
    const int* __restrict__ rp1, const float2* __restrict__ rec1, const ushort* __restrict__ h1,
    const int* __restrict__ rp2, const float2* __restrict__ rec2, const ushort* __restrict__ h2,
    float* __restrict__ out) {
    const int conv = blockIdx.y;
    const int* rp = conv ? rp2 : rp1;
    const float2* rec = conv ? rec2 : rec1;
    const ushort* h = conv ? h2 : h1;
    float* outb = conv ? out : out + (size_t)NS * DD;  // conv1 -> rows [NS,N)
    const int node = blockIdx.x * 4 + (threadIdx.x >> 6);
    if (node >= NS) return;
    const int lane = threadIdx.x & 63, sub = lane >> 5, l32 = lane & 31;
    const int beg = rp[node], end = rp[node + 1];
    float4 acc = make_float4(0.f, 0.f, 0.f, 0.f);
    float es = 0.f;
    for (int e = beg + sub; e < end; e += 2) {
        const float2 r = rec[e];
        const int s = __float_as_int(r.x);
        const float ee = r.y;
        es += ee;
        const ushort4 hv = *(const ushort4*)(h + (size_t)s * DD + l32 * 4);
        acc.x += ee * bf2f(hv.x);
        acc.y += ee * bf2f(hv.y);
        acc.z += ee * bf2f(hv.z);
        acc.w += ee * bf2f(hv.w);
    }
    acc.x += __shfl_xor(acc.x, 32);
    acc.y += __shfl_xor(acc.y, 32);
    acc.z += __shfl_xor(acc.z, 32);
    acc.w += __shfl_xor(acc.w, 32);
    es += __shfl_xor(es, 32);
    if (sub == 0) {
        const float inv = 1.f / (es + 1e-16f);
        float4 o;
        o.x = fmaxf(acc.x * inv, 0.f);
        o.y = fmaxf(acc.y * inv, 0.f);
        o.z = fmaxf(acc.z * inv, 0.f);
        o.w = fmaxf(acc.w * inv, 0.f);
        *(float4*)(outb + (size_t)node * DD + l32 * 4) = o;
    }
}

extern "C" void kernel_launch(void* const* d_in, const int* in_sizes, int n_in,
                              void* d_out, int out_size, void* d_ws, size_t ws_size,
                              hipStream_t stream) {
    const int* ei  = (const int*)d_in[0];
    const int* pei = (const int*)d_in[1];
    const int* aei = (const int*)d_in[2];
    const float* xs  = (const float*)d_in[3];
    const float* xt  = (const float*)d_in[4];
    const float* Ws  = (const float*)d_in[5];
    const float* bs  = (const float*)d_in[6];
    const float* Wt  = (const float*)d_in[7];
    const float* bt  = (const float*)d_in[8];
    const float* W1  = (const float*)d_in[9];
    const float* a1s = (const float*)d_in[10];
    const float* a1d = (const float*)d_in[11];
    const float* W2  = (const float*)d_in[12];
    const float* a2s = (const float*)d_in[13];
    const float* a2d = (const float*)d_in[14];
    float* ws  = (float*)d_ws;
    float* out = (float*)d_out;

    ushort* h1 = (ushort*)(ws + OFF_H1);
    ushort* h2 = (ushort*)(ws + OFF_H2);
    int* deg1 = (int*)(ws + OFF_DEG1);
    int* rp1  = (int*)(ws + OFF_RP1);
    int* rp2  = (int*)(ws + OFF_RP2);
    int* cur1 = (int*)(ws + OFF_CUR1);
    int* cur2 = (int*)(ws + OFF_CUR2);
    int* psum = (int*)(ws + OFF_PS);
    int* pref = (int*)(ws + OFF_PREF);
    float2* rec1 = (float2*)(ws + OFF_REC1);
    float2* rec2 = (float2*)(ws + OFF_REC2);

    hipMemsetAsync(deg1, 0, 2 * NS * sizeof(int), stream);  // DEG1,DEG2 contiguous

    k_gemm<<<dim3((NS + 63) / 64, 2), 256, 0, stream>>>(
        xs, xt, Ws, bs, Wt, bt, W1, a1s, a1d, W2, a2s, a2d,
        h1, h2, ws + OFF_AS1, ws + OFF_AD1, ws + OFF_AS2, ws + OFF_AD2);

    const int eb = (ETOT + 255) / 256;
    k_count_both<<<eb, 256, 0, stream>>>(ei, pei, aei, deg1, deg1 + NS);
    k_scan1<<<dim3(49, 2), 256, 0, stream>>>(deg1, psum);
    k_scan2<<<1, 128, 0, stream>>>(psum, pref);
    k_scan3<<<dim3(49, 2), 256, 0, stream>>>(deg1, pref, rp1, cur1, rp2, cur2);
    k_fill_both<<<eb, 256, 0, stream>>>(ei, pei, aei,
                                        ws + OFF_AS1, ws + OFF_AD1, ws + OFF_AS2, ws + OFF_AD2,
                                        cur1, rec1, cur2, rec2);
    k_gather<<<dim3(NS / 4, 2), 256, 0, stream>>>(rp1, rec1, h1, rp2, rec2, h2, out);
}

// Round 8
// 366.468 us; speedup vs baseline: 8.9696x; 1.1074x over previous
//
#include <hip/hip_runtime.h>
#include <hip/hip_bf16.h>

// Problem constants
#define E0   500000
#define NS   50000
#define DD   128
#define ETOT (2*E0 + NS)   // per-conv edges incl. self loops = 1,050,000

// workspace layout (in 4B float units)
#define OFF_H1   0UL          // ushort[100000*128] = 6.4M floats
#define OFF_H2   6400000UL
#define OFF_AS1  12800000UL   // float[100000]
#define OFF_AD1  12900000UL
#define OFF_AS2  13000000UL
#define OFF_AD2  13100000UL
#define OFF_DEG1 13200000UL
#define OFF_DEG2 13250000UL
#define OFF_RP1  13300000UL   // 50001 ints
#define OFF_RP2  13351000UL
#define OFF_CUR1 13402000UL
#define OFF_CUR2 13452000UL
#define OFF_PS   13502000UL   // 128 ints
#define OFF_PREF 13502128UL   // 128 ints
#define OFF_REC1 13502256UL   // float2[1100000]
#define OFF_REC2 15702256UL
// total ~17.9M floats = 71.6 MB

typedef __bf16 bf16x8 __attribute__((ext_vector_type(8)));
typedef float f32x4 __attribute__((ext_vector_type(4)));

__device__ __forceinline__ ushort f2bf(float f) {
    uint b = __float_as_uint(f);
    return (ushort)((b + 0x7FFFu + ((b >> 16) & 1u)) >> 16);
}
__device__ __forceinline__ float bf2f(ushort u) { return __uint_as_float(((uint)u) << 16); }
__device__ __forceinline__ uint pk2(float a, float b) {
    return (uint)f2bf(a) | ((uint)f2bf(b) << 16);
}

// ---------------------------------------------------------------------------
// Fused dense kernel (MFMA bf16): x = xin@W0.T + b0 ; h1 = x@W1.T ; h2 = x@W2.T
// (identical to the round-4 kernel that passed)
// ---------------------------------------------------------------------------
__device__ __forceinline__ void stage_w_bf16(ushort* Wl, const float* __restrict__ W, int tid) {
#pragma unroll
    for (int i = 0; i < 8; i++) {
        const int idx = i * 256 + tid;          // 2048 chunks of 16B
        const int row = idx >> 4, ch = idx & 15;
        const float4 f0 = *(const float4*)(W + row * DD + ch * 8);
        const float4 f1 = *(const float4*)(W + row * DD + ch * 8 + 4);
        uint4 v = make_uint4(pk2(f0.x, f0.y), pk2(f0.z, f0.w), pk2(f1.x, f1.y), pk2(f1.z, f1.w));
        *(uint4*)((char*)Wl + ((row * 256 + ch * 16) ^ ((row & 7) << 4))) = v;
    }
}

__device__ __forceinline__ void stage_x(ushort* Xl, const float* __restrict__ xin,
                                        int row0, int tid) {
#pragma unroll
    for (int i = 0; i < 4; i++) {
        const int idx = i * 256 + tid;          // 1024 chunks of 16B
        const int r = idx >> 4, ch = idx & 15;
        const int gr = row0 + r;
        float4 f0 = make_float4(0.f, 0.f, 0.f, 0.f), f1 = f0;
        if (gr < NS) {
            f0 = *(const float4*)(xin + (size_t)gr * DD + ch * 8);
            f1 = *(const float4*)(xin + (size_t)gr * DD + ch * 8 + 4);
        }
        uint4 v = make_uint4(pk2(f0.x, f0.y), pk2(f0.z, f0.w), pk2(f1.x, f1.y), pk2(f1.z, f1.w));
        *(uint4*)((char*)Xl + ((r * 256 + ch * 16) ^ ((r & 7) << 4))) = v;
    }
}

__device__ __forceinline__ void mfma_phase(const ushort* Wl, const ushort* Xl,
                                           int wrow, int lane, f32x4 acc[8]) {
    const int l15 = lane & 15, q = lane >> 4;
    bf16x8 a[4];
#pragma unroll
    for (int ks = 0; ks < 4; ks++) {
        const int row = wrow + l15;
        const int byte = (row * 256 + (ks * 32 + q * 8) * 2) ^ ((row & 7) << 4);
        a[ks] = *(const bf16x8*)((const char*)Xl + byte);
    }
#pragma unroll
    for (int nt = 0; nt < 8; nt++) {
        const int n = nt * 16 + l15;
#pragma unroll
        for (int ks = 0; ks < 4; ks++) {
            const int byte = (n * 256 + (ks * 32 + q * 8) * 2) ^ ((n & 7) << 4);
            bf16x8 b = *(const bf16x8*)((const char*)Wl + byte);
            acc[nt] = __builtin_amdgcn_mfma_f32_16x16x32_bf16(a[ks], b, acc[nt], 0, 0, 0);
        }
    }
}

__device__ __forceinline__ void epi23(const f32x4 acc[8], int half, int row0, int wrow,
                                      int lane, const float* __restrict__ avs,
                                      const float* __restrict__ avd,
                                      ushort* __restrict__ h,
                                      float* __restrict__ as_, float* __restrict__ ad_) {
    const int l15 = lane & 15, q = lane >> 4;
    float vs[8], vd[8];
#pragma unroll
    for (int nt = 0; nt < 8; nt++) { vs[nt] = avs[nt * 16 + l15]; vd[nt] = avd[nt * 16 + l15]; }
#pragma unroll
    for (int r = 0; r < 4; r++) {
        const int gr = row0 + wrow + q * 4 + r;
        const bool ok = gr < NS;
        const size_t node = (size_t)(half * NS + gr);
        float ps = 0.f, pd = 0.f;
#pragma unroll
        for (int nt = 0; nt < 8; nt++) {
            const float v = acc[nt][r];
            ps += v * vs[nt];
            pd += v * vd[nt];
            if (ok) h[node * DD + nt * 16 + l15] = f2bf(v);
        }
#pragma unroll
        for (int m = 8; m; m >>= 1) { ps += __shfl_xor(ps, m); pd += __shfl_xor(pd, m); }
        if (ok && l15 == 0) { as_[node] = ps; ad_[node] = pd; }
    }
}

__global__ __launch_bounds__(256) void k_gemm(
    const float* __restrict__ xs, const float* __restrict__ xt,
    const float* __restrict__ Ws, const float* __restrict__ bs,
    const float* __restrict__ Wt, const float* __restrict__ bt,
    const float* __restrict__ W1, const float* __restrict__ a1s, const float* __restrict__ a1d,
    const float* __restrict__ W2, const float* __restrict__ a2s, const float* __restrict__ a2d,
    ushort* __restrict__ h1, ushort* __restrict__ h2,
    float* __restrict__ as1, float* __restrict__ ad1,
    float* __restrict__ as2, float* __restrict__ ad2) {
    __shared__ __align__(16) ushort Wl[128 * 128];  // 32 KB
    __shared__ __align__(16) ushort Xl[64 * 128];   // 16 KB
    const int tid = threadIdx.x;
    const int lane = tid & 63, wv = tid >> 6, wrow = wv * 16;
    const int l15 = lane & 15, q = lane >> 4;
    const int half = blockIdx.y;
    const int row0 = blockIdx.x * 64;
    const float* xin = half ? xt : xs;
    const float* W0  = half ? Wt : Ws;
    const float* b0  = half ? bt : bs;

    stage_w_bf16(Wl, W0, tid);
    stage_x(Xl, xin, row0, tid);
    __syncthreads();

    f32x4 acc[8];
#pragma unroll
    for (int nt = 0; nt < 8; nt++) acc[nt] = 0.f;
    mfma_phase(Wl, Xl, wrow, lane, acc);

#pragma unroll
    for (int nt = 0; nt < 8; nt++) {
        const float bvv = b0[nt * 16 + l15];
#pragma unroll
        for (int r = 0; r < 4; r++) {
            const int row = wrow + q * 4 + r;
            const int byte = (row * 256 + (nt * 16 + l15) * 2) ^ ((row & 7) << 4);
            *(ushort*)((char*)Xl + byte) = f2bf(acc[nt][r] + bvv);
        }
    }
    __syncthreads();
    stage_w_bf16(Wl, W1, tid);
    __syncthreads();

#pragma unroll
    for (int nt = 0; nt < 8; nt++) acc[nt] = 0.f;
    mfma_phase(Wl, Xl, wrow, lane, acc);
    epi23(acc, half, row0, wrow, lane, a1s, a1d, h1, as1, ad1);

    __syncthreads();
    stage_w_bf16(Wl, W2, tid);
    __syncthreads();

#pragma unroll
    for (int nt = 0; nt < 8; nt++) acc[nt] = 0.f;
    mfma_phase(Wl, Xl, wrow, lane, acc);
    epi23(acc, half, row0, wrow, lane, a2s, a2d, h2, as2, ad2);
}

// ---------------------------------------------------------------------------
// Edge pipeline: count -> scan(3 stages) -> fill (CSR) -> gather.
// conv1: (src, dst+NS) ++ author ++ loops[NS,N) ; out rows [NS,N)
// conv2: (dst+NS, src) ++ paper  ++ loops[0,NS) ; out rows [0,NS)
// ---------------------------------------------------------------------------
__global__ void k_count_both(const int* __restrict__ ei, const int* __restrict__ pei,
                             const int* __restrict__ aei,
                             int* __restrict__ deg1, int* __restrict__ deg2) {
    const int e = blockIdx.x * 256 + threadIdx.x;
    if (e >= ETOT) return;
    if (e < E0) {
        const int a = ei[e], b = ei[E0 + e];
        atomicAdd(&deg1[b], 1);
        atomicAdd(&deg2[a], 1);
    } else if (e < 2 * E0) {
        const int k = e - E0;
        const int d1 = aei[E0 + k];
        if (d1 >= NS) atomicAdd(&deg1[d1 - NS], 1);
        const int d2 = pei[E0 + k];
        if (d2 < NS) atomicAdd(&deg2[d2], 1);
    } else {
        const int k = e - 2 * E0;
        atomicAdd(&deg1[k], 1);
        atomicAdd(&deg2[k], 1);
    }
}

__device__ __forceinline__ int wave_incl_scan(int x, int lane) {
#pragma unroll
    for (int off = 1; off < 64; off <<= 1) {
        const int v = __shfl_up(x, off);
        if (lane >= off) x += v;
    }
    return x;
}

__device__ __forceinline__ int4 load_deg4(const int* __restrict__ d, int idx) {
    if (idx + 3 < NS) return *(const int4*)(d + idx);
    int4 v = make_int4(0, 0, 0, 0);
    if (idx + 0 < NS) v.x = d[idx + 0];
    if (idx + 1 < NS) v.y = d[idx + 1];
    if (idx + 2 < NS) v.z = d[idx + 2];
    if (idx + 3 < NS) v.w = d[idx + 3];
    return v;
}

__global__ __launch_bounds__(256) void k_scan1(const int* __restrict__ deg,
                                               int* __restrict__ psum) {
    const int conv = blockIdx.y, blk = blockIdx.x, t = threadIdx.x;
    const int* d = deg + conv * NS;
    const int4 v = load_deg4(d, blk * 1024 + t * 4);
    int s = v.x + v.y + v.z + v.w;
#pragma unroll
    for (int m = 32; m; m >>= 1) s += __shfl_xor(s, m);
    __shared__ int wsum[4];
    const int lane = t & 63, wv = t >> 6;
    if (lane == 0) wsum[wv] = s;
    __syncthreads();
    if (t == 0) psum[conv * 64 + blk] = wsum[0] + wsum[1] + wsum[2] + wsum[3];
}

__global__ __launch_bounds__(128) void k_scan2(const int* __restrict__ psum,
                                               int* __restrict__ pref) {
    const int t = threadIdx.x;
    const int w = t >> 6, lane = t & 63;
    const int x = (lane < 49) ? psum[w * 64 + lane] : 0;
    const int incl = wave_incl_scan(x, lane);
    if (lane < 49) pref[w * 64 + lane] = incl - x;
}

__global__ __launch_bounds__(256) void k_scan3(const int* __restrict__ deg,
                                               const int* __restrict__ pref,
                                               int* __restrict__ rp1, int* __restrict__ cur1,
                                               int* __restrict__ rp2, int* __restrict__ cur2) {
    const int conv = blockIdx.y, blk = blockIdx.x, t = threadIdx.x;
    const int* d = deg + conv * NS;
    int* rp  = conv ? rp2  : rp1;
    int* cur = conv ? cur2 : cur1;
    const int idx = blk * 1024 + t * 4;
    const int4 v = load_deg4(d, idx);
    const int tsum = v.x + v.y + v.z + v.w;
    const int lane = t & 63, wv = t >> 6;
    const int incl = wave_incl_scan(tsum, lane);
    __shared__ int wsum[4];
    if (lane == 63) wsum[wv] = incl;
    __syncthreads();
    int woff = 0;
#pragma unroll
    for (int i = 0; i < 4; i++) woff += (i < wv) ? wsum[i] : 0;
    int ex = pref[conv * 64 + blk] + woff + (incl - tsum);
    if (idx + 0 < NS) { rp[idx + 0] = ex; cur[idx + 0] = ex; } ex += v.x;
    if (idx + 1 < NS) { rp[idx + 1] = ex; cur[idx + 1] = ex; } ex += v.y;
    if (idx + 2 < NS) { rp[idx + 2] = ex; cur[idx + 2] = ex; } ex += v.z;
    if (idx + 3 < NS) { rp[idx + 3] = ex; cur[idx + 3] = ex; } ex += v.w;
    if (blk == 48 && t == 0)
        rp[NS] = pref[conv * 64 + 48] + wsum[0] + wsum[1] + wsum[2] + wsum[3];
}

__device__ __forceinline__ float att_ee(float as_v, float ad_v) {
    float v = as_v + ad_v;
    v = v > 0.f ? v : 0.2f * v;
    return __expf(v);
}

__global__ void k_fill_both(const int* __restrict__ ei, const int* __restrict__ pei,
                            const int* __restrict__ aei,
                            const float* __restrict__ as1, const float* __restrict__ ad1,
                            const float* __restrict__ as2, const float* __restrict__ ad2,
                            int* __restrict__ cur1, float2* __restrict__ rec1,
                            int* __restrict__ cur2, float2* __restrict__ rec2) {
    const int e = blockIdx.x * 256 + threadIdx.x;
    if (e >= ETOT) return;
    if (e < E0) {
        const int a = ei[e], b = ei[E0 + e];
        {   // conv1: s=a, d=b+NS
            const float ee = att_ee(as1[a], ad1[b + NS]);
            const int pos = atomicAdd(&cur1[b], 1);
            rec1[pos] = make_float2(__int_as_float(a), ee);
        }
        {   // conv2: s=b+NS, d=a
            const float ee = att_ee(as2[b + NS], ad2[a]);
            const int pos = atomicAdd(&cur2[a], 1);
            rec2[pos] = make_float2(__int_as_float(b + NS), ee);
        }
    } else if (e < 2 * E0) {
        const int k = e - E0;
        const int s1 = aei[k], d1 = aei[E0 + k];
        if (d1 >= NS) {
            const float ee = att_ee(as1[s1], ad1[d1]);
            const int pos = atomicAdd(&cur1[d1 - NS], 1);
            rec1[pos] = make_float2(__int_as_float(s1), ee);
        }
        const int s2 = pei[k], d2 = pei[E0 + k];
        if (d2 < NS) {
            const float ee = att_ee(as2[s2], ad2[d2]);
            const int pos = atomicAdd(&cur2[d2], 1);
            rec2[pos] = make_float2(__int_as_float(s2), ee);
        }
    } else {
        const int k = e - 2 * E0;
        {
            const float ee = att_ee(as1[NS + k], ad1[NS + k]);
            const int pos = atomicAdd(&cur1[k], 1);
            rec1[pos] = make_float2(__int_as_float(NS + k), ee);
        }
        {
            const float ee = att_ee(as2[k], ad2[k]);
            const int pos = atomicAdd(&cur2[k], 1);
            rec2[pos] = make_float2(__int_as_float(k), ee);
        }
    }
}

// ---------------------------------------------------------------------------
// Gather: one wave per dst node; 4 groups x 16 lanes. Each group reads a full
// 256B h-row (uint4/lane). Group g owns edge quads {beg+4g+16t .. +3}: the
// residues mod 16 partition [beg,end) exactly once. 4 independent rec-load ->
// row-load chains per group (16 per wave) hide latency.
// ---------------------------------------------------------------------------
__device__ __forceinline__ void fma8(float acc[8], float e, const uint4 q) {
    acc[0] += e * __uint_as_float(q.x << 16);
    acc[1] += e * __uint_as_float(q.x & 0xFFFF0000u);
    acc[2] += e * __uint_as_float(q.y << 16);
    acc[3] += e * __uint_as_float(q.y & 0xFFFF0000u);
    acc[4] += e * __uint_as_float(q.z << 16);
    acc[5] += e * __uint_as_float(q.z & 0xFFFF0000u);
    acc[6] += e * __uint_as_float(q.w << 16);
    acc[7] += e * __uint_as_float(q.w & 0xFFFF0000u);
}

__global__ __launch_bounds__(256) void k_gather(
    const int* __restrict__ rp1, const float2* __restrict__ rec1, const ushort* __restrict__ h1,
    const int* __restrict__ rp2, const float2* __restrict__ rec2, const ushort* __restrict__ h2,
    float* __restrict__ out) {
    const int conv = blockIdx.y;
    const int* rp = conv ? rp2 : rp1;
    const float2* rec = conv ? rec2 : rec1;
    const ushort* h = conv ? h2 : h1;
    float* outb = conv ? out : out + (size_t)NS * DD;  // conv1 -> rows [NS,N)
    const int node = blockIdx.x * 4 + (threadIdx.x >> 6);
    const int lane = threadIdx.x & 63;
    const int g = lane >> 4, l16 = lane & 15;
    const int beg = rp[node], end = rp[node + 1];
    float acc[8];
#pragma unroll
    for (int i = 0; i < 8; i++) acc[i] = 0.f;
    float es = 0.f;

    for (int e = beg + g * 4; e < end; e += 16) {
        float w[4];
        int s[4];
#pragma unroll
        for (int u = 0; u < 4; u++) {
            const bool ok = (e + u < end);
            const float2 r = ok ? rec[e + u] : make_float2(0.f, 0.f);
            s[u] = ok ? __float_as_int(r.x) : 0;
            w[u] = r.y;
        }
        uint4 q[4];
#pragma unroll
        for (int u = 0; u < 4; u++)
            q[u] = *(const uint4*)(h + (size_t)s[u] * DD + l16 * 8);
#pragma unroll
        for (int u = 0; u < 4; u++) {
            es += w[u];
            fma8(acc, w[u], q[u]);
        }
    }

    // reduce across the 4 groups
#pragma unroll
    for (int i = 0; i < 8; i++) {
        acc[i] += __shfl_xor(acc[i], 16);
        acc[i] += __shfl_xor(acc[i], 32);
    }
    es += __shfl_xor(es, 16);
    es += __shfl_xor(es, 32);

    if (g == 0) {
        const float inv = 1.f / (es + 1e-16f);
        float4 o0, o1;
        o0.x = fmaxf(acc[0] * inv, 0.f);
        o0.y = fmaxf(acc[1] * inv, 0.f);
        o0.z = fmaxf(acc[2] * inv, 0.f);
        o0.w = fmaxf(acc[3] * inv, 0.f);
        o1.x = fmaxf(acc[4] * inv, 0.f);
        o1.y = fmaxf(acc[5] * inv, 0.f);
        o1.z = fmaxf(acc[6] * inv, 0.f);
        o1.w = fmaxf(acc[7] * inv, 0.f);
        *(float4*)(outb + (size_t)node * DD + l16 * 8) = o0;
        *(float4*)(outb + (size_t)node * DD + l16 * 8 + 4) = o1;
    }
}

extern "C" void kernel_launch(void* const* d_in, const int* in_sizes, int n_in,
                              void* d_out, int out_size, void* d_ws, size_t ws_size,
                              hipStream_t stream) {
    const int* ei  = (const int*)d_in[0];
    const int* pei = (const int*)d_in[1];
    const int* aei = (const int*)d_in[2];
    const float* xs  = (const float*)d_in[3];
    const float* xt  = (const float*)d_in[4];
    const float* Ws  = (const float*)d_in[5];
    const float* bs  = (const float*)d_in[6];
    const float* Wt  = (const float*)d_in[7];
    const float* bt  = (const float*)d_in[8];
    const float* W1  = (const float*)d_in[9];
    const float* a1s = (const float*)d_in[10];
    const float* a1d = (const float*)d_in[11];
    const float* W2  = (const float*)d_in[12];
    const float* a2s = (const float*)d_in[13];
    const float* a2d = (const float*)d_in[14];
    float* ws  = (float*)d_ws;
    float* out = (float*)d_out;

    ushort* h1 = (ushort*)(ws + OFF_H1);
    ushort* h2 = (ushort*)(ws + OFF_H2);
    int* deg1 = (int*)(ws + OFF_DEG1);
    int* rp1  = (int*)(ws + OFF_RP1);
    int* rp2  = (int*)(ws + OFF_RP2);
    int* cur1 = (int*)(ws + OFF_CUR1);
    int* cur2 = (int*)(ws + OFF_CUR2);
    int* psum = (int*)(ws + OFF_PS);
    int* pref = (int*)(ws + OFF_PREF);
    float2* rec1 = (float2*)(ws + OFF_REC1);
    float2* rec2 = (float2*)(ws + OFF_REC2);

    hipMemsetAsync(deg1, 0, 2 * NS * sizeof(int), stream);  // DEG1,DEG2 contiguous

    k_gemm<<<dim3((NS + 63) / 64, 2), 256, 0, stream>>>(
        xs, xt, Ws, bs, Wt, bt, W1, a1s, a1d, W2, a2s, a2d,
        h1, h2, ws + OFF_AS1, ws + OFF_AD1, ws + OFF_AS2, ws + OFF_AD2);

    const int eb = (ETOT + 255) / 256;
    k_count_both<<<eb, 256, 0, stream>>>(ei, pei, aei, deg1, deg1 + NS);
    k_scan1<<<dim3(49, 2), 256, 0, stream>>>(deg1, psum);
    k_scan2<<<1, 128, 0, stream>>>(psum, pref);
    k_scan3<<<dim3(49, 2), 256, 0, stream>>>(deg1, pref, rp1, cur1, rp2, cur2);
    k_fill_both<<<eb, 256, 0, stream>>>(ei, pei, aei,
                                        ws + OFF_AS1, ws + OFF_AD1, ws + OFF_AS2, ws + OFF_AD2,
                                        cur1, rec1, cur2, rec2);
    k_gather<<<dim3(NS / 4, 2), 256, 0, stream>>>(rp1, rec1, h1, rp2, rec2, h2, out);
}

// Round 9
// 319.784 us; speedup vs baseline: 10.2790x; 1.1460x over previous
//
#include <hip/hip_runtime.h>
#include <hip/hip_bf16.h>

// Problem constants
#define E0   500000
#define NS   50000
#define DD   128
#define ETOT (2*E0 + NS)   // per-conv edges incl. self loops = 1,050,000

#define GEMM_BLOCKS 1564   // 782 row-tiles x 2 halves
#define EDGE_BLOCKS 4102   // ceil(ETOT/256)

// workspace layout (in 4B units)
#define OFF_H1    0UL          // ushort[100000*128] = 6.4M floats
#define OFF_H2    6400000UL
#define OFF_AS1   12800000UL   // float[100000]
#define OFF_AD1   12900000UL
#define OFF_AS2   13000000UL
#define OFF_AD2   13100000UL
#define OFF_DEG1  13200000UL   // int[50000]
#define OFF_DEG2  13250000UL   // contiguous with DEG1
#define OFF_RP1   13300000UL   // int[50001]
#define OFF_RP2   13351000UL
#define OFF_PS    13402000UL   // int[128]
#define OFF_PREF  13402128UL   // int[128]
#define OFF_SLOT1 13402256UL   // int[1050000]
#define OFF_SLOT2 14452256UL
#define OFF_REC1  15502256UL   // int[1050000] (src only)
#define OFF_REC2  16552256UL
// total 17,602,256 * 4B = 70.4 MB

typedef __bf16 bf16x8 __attribute__((ext_vector_type(8)));
typedef float f32x4 __attribute__((ext_vector_type(4)));

__device__ __forceinline__ ushort f2bf(float f) {
    uint b = __float_as_uint(f);
    return (ushort)((b + 0x7FFFu + ((b >> 16) & 1u)) >> 16);
}
__device__ __forceinline__ uint pk2(float a, float b) {
    return (uint)f2bf(a) | ((uint)f2bf(b) << 16);
}

// ---------------------------------------------------------------------------
// GEMM path helpers (identical math to the round-4/8 kernel that passed)
// ---------------------------------------------------------------------------
__device__ __forceinline__ void stage_w_bf16(ushort* Wl, const float* __restrict__ W, int tid) {
#pragma unroll
    for (int i = 0; i < 8; i++) {
        const int idx = i * 256 + tid;          // 2048 chunks of 16B
        const int row = idx >> 4, ch = idx & 15;
        const float4 f0 = *(const float4*)(W + row * DD + ch * 8);
        const float4 f1 = *(const float4*)(W + row * DD + ch * 8 + 4);
        uint4 v = make_uint4(pk2(f0.x, f0.y), pk2(f0.z, f0.w), pk2(f1.x, f1.y), pk2(f1.z, f1.w));
        *(uint4*)((char*)Wl + ((row * 256 + ch * 16) ^ ((row & 7) << 4))) = v;
    }
}

__device__ __forceinline__ void stage_x(ushort* Xl, const float* __restrict__ xin,
                                        int row0, int tid) {
#pragma unroll
    for (int i = 0; i < 4; i++) {
        const int idx = i * 256 + tid;          // 1024 chunks of 16B
        const int r = idx >> 4, ch = idx & 15;
        const int gr = row0 + r;
        float4 f0 = make_float4(0.f, 0.f, 0.f, 0.f), f1 = f0;
        if (gr < NS) {
            f0 = *(const float4*)(xin + (size_t)gr * DD + ch * 8);
            f1 = *(const float4*)(xin + (size_t)gr * DD + ch * 8 + 4);
        }
        uint4 v = make_uint4(pk2(f0.x, f0.y), pk2(f0.z, f0.w), pk2(f1.x, f1.y), pk2(f1.z, f1.w));
        *(uint4*)((char*)Xl + ((r * 256 + ch * 16) ^ ((r & 7) << 4))) = v;
    }
}

__device__ __forceinline__ void mfma_phase(const ushort* Wl, const ushort* Xl,
                                           int wrow, int lane, f32x4 acc[8]) {
    const int l15 = lane & 15, q = lane >> 4;
    bf16x8 a[4];
#pragma unroll
    for (int ks = 0; ks < 4; ks++) {
        const int row = wrow + l15;
        const int byte = (row * 256 + (ks * 32 + q * 8) * 2) ^ ((row & 7) << 4);
        a[ks] = *(const bf16x8*)((const char*)Xl + byte);
    }
#pragma unroll
    for (int nt = 0; nt < 8; nt++) {
        const int n = nt * 16 + l15;
#pragma unroll
        for (int ks = 0; ks < 4; ks++) {
            const int byte = (n * 256 + (ks * 32 + q * 8) * 2) ^ ((n & 7) << 4);
            bf16x8 b = *(const bf16x8*)((const char*)Wl + byte);
            acc[nt] = __builtin_amdgcn_mfma_f32_16x16x32_bf16(a[ks], b, acc[nt], 0, 0, 0);
        }
    }
}

__device__ __forceinline__ void epi23(const f32x4 acc[8], int half, int row0, int wrow,
                                      int lane, const float* __restrict__ avs,
                                      const float* __restrict__ avd,
                                      ushort* __restrict__ h,
                                      float* __restrict__ as_, float* __restrict__ ad_) {
    const int l15 = lane & 15, q = lane >> 4;
    float vs[8], vd[8];
#pragma unroll
    for (int nt = 0; nt < 8; nt++) { vs[nt] = avs[nt * 16 + l15]; vd[nt] = avd[nt * 16 + l15]; }
#pragma unroll
    for (int r = 0; r < 4; r++) {
        const int gr = row0 + wrow + q * 4 + r;
        const bool ok = gr < NS;
        const size_t node = (size_t)(half * NS + gr);
        float ps = 0.f, pd = 0.f;
#pragma unroll
        for (int nt = 0; nt < 8; nt++) {
            const float v = acc[nt][r];
            ps += v * vs[nt];
            pd += v * vd[nt];
            if (ok) h[node * DD + nt * 16 + l15] = f2bf(v);
        }
#pragma unroll
        for (int m = 8; m; m >>= 1) { ps += __shfl_xor(ps, m); pd += __shfl_xor(pd, m); }
        if (ok && l15 == 0) { as_[node] = ps; ad_[node] = pd; }
    }
}

// ---------------------------------------------------------------------------
// FAT kernel: blocks [0, GEMM_BLOCKS) run the fused dense GEMM; blocks
// [GEMM_BLOCKS, GEMM_BLOCKS+EDGE_BLOCKS) run CSR fill (no atomics: slot from
// count + rowptr). The latency-bound fill hides under the MFMA-bound gemm.
// ---------------------------------------------------------------------------
__global__ __launch_bounds__(256) void k_fat(
    const float* __restrict__ xs, const float* __restrict__ xt,
    const float* __restrict__ Ws, const float* __restrict__ bs,
    const float* __restrict__ Wt, const float* __restrict__ bt,
    const float* __restrict__ W1, const float* __restrict__ a1s, const float* __restrict__ a1d,
    const float* __restrict__ W2, const float* __restrict__ a2s, const float* __restrict__ a2d,
    ushort* __restrict__ h1, ushort* __restrict__ h2,
    float* __restrict__ as1, float* __restrict__ ad1,
    float* __restrict__ as2, float* __restrict__ ad2,
    const int* __restrict__ ei, const int* __restrict__ pei, const int* __restrict__ aei,
    const int* __restrict__ rp1, const int* __restrict__ rp2,
    const int* __restrict__ slot1, const int* __restrict__ slot2,
    int* __restrict__ rec1, int* __restrict__ rec2) {
    __shared__ __align__(16) ushort Wl[128 * 128];  // 32 KB
    __shared__ __align__(16) ushort Xl[64 * 128];   // 16 KB
    const int bid = blockIdx.x;
    const int tid = threadIdx.x;

    if (bid >= GEMM_BLOCKS) {
        // ---------------- fill path ----------------
        const int e = (bid - GEMM_BLOCKS) * 256 + tid;
        if (e >= ETOT) return;
        if (e < E0) {
            const int a = ei[e], b = ei[E0 + e];
            rec1[rp1[b] + slot1[e]] = a;          // conv1: s=a, dl=b
            rec2[rp2[a] + slot2[e]] = b + NS;     // conv2: s=b+NS, dl=a
        } else if (e < 2 * E0) {
            const int k = e - E0;
            const int s1 = aei[k], d1 = aei[E0 + k];
            if (d1 >= NS) rec1[rp1[d1 - NS] + slot1[e]] = s1;
            const int s2 = pei[k], d2 = pei[E0 + k];
            if (d2 < NS) rec2[rp2[d2] + slot2[e]] = s2;
        } else {
            const int k = e - 2 * E0;
            rec1[rp1[k] + slot1[e]] = NS + k;
            rec2[rp2[k] + slot2[e]] = k;
        }
        return;
    }

    // ---------------- gemm path (identical to proven kernel) ----------------
    const int lane = tid & 63, wv = tid >> 6, wrow = wv * 16;
    const int l15 = lane & 15, q = lane >> 4;
    const int half = (bid >= 782) ? 1 : 0;
    const int row0 = (bid - half * 782) * 64;
    const float* xin = half ? xt : xs;
    const float* W0  = half ? Wt : Ws;
    const float* b0  = half ? bt : bs;

    stage_w_bf16(Wl, W0, tid);
    stage_x(Xl, xin, row0, tid);
    __syncthreads();

    f32x4 acc[8];
#pragma unroll
    for (int nt = 0; nt < 8; nt++) acc[nt] = 0.f;
    mfma_phase(Wl, Xl, wrow, lane, acc);

#pragma unroll
    for (int nt = 0; nt < 8; nt++) {
        const float bvv = b0[nt * 16 + l15];
#pragma unroll
        for (int r = 0; r < 4; r++) {
            const int row = wrow + q * 4 + r;
            const int byte = (row * 256 + (nt * 16 + l15) * 2) ^ ((row & 7) << 4);
            *(ushort*)((char*)Xl + byte) = f2bf(acc[nt][r] + bvv);
        }
    }
    __syncthreads();
    stage_w_bf16(Wl, W1, tid);
    __syncthreads();

#pragma unroll
    for (int nt = 0; nt < 8; nt++) acc[nt] = 0.f;
    mfma_phase(Wl, Xl, wrow, lane, acc);
    epi23(acc, half, row0, wrow, lane, a1s, a1d, h1, as1, ad1);

    __syncthreads();
    stage_w_bf16(Wl, W2, tid);
    __syncthreads();

#pragma unroll
    for (int nt = 0; nt < 8; nt++) acc[nt] = 0.f;
    mfma_phase(Wl, Xl, wrow, lane, acc);
    epi23(acc, half, row0, wrow, lane, a2s, a2d, h2, as2, ad2);
}

// ---------------------------------------------------------------------------
// Count: histogram degrees AND record each edge's slot (atomic return value),
// stored coalesced. conv1: (src, dst+NS) ++ author ++ loops[NS,N).
// conv2: (dst+NS, src) ++ paper ++ loops[0,NS).
// ---------------------------------------------------------------------------
__global__ void k_count_both(const int* __restrict__ ei, const int* __restrict__ pei,
                             const int* __restrict__ aei,
                             int* __restrict__ deg1, int* __restrict__ deg2,
                             int* __restrict__ slot1, int* __restrict__ slot2) {
    const int e = blockIdx.x * 256 + threadIdx.x;
    if (e >= ETOT) return;
    if (e < E0) {
        const int a = ei[e], b = ei[E0 + e];
        slot1[e] = atomicAdd(&deg1[b], 1);
        slot2[e] = atomicAdd(&deg2[a], 1);
    } else if (e < 2 * E0) {
        const int k = e - E0;
        const int d1 = aei[E0 + k];
        if (d1 >= NS) slot1[e] = atomicAdd(&deg1[d1 - NS], 1);
        const int d2 = pei[E0 + k];
        if (d2 < NS) slot2[e] = atomicAdd(&deg2[d2], 1);
    } else {
        const int k = e - 2 * E0;
        slot1[e] = atomicAdd(&deg1[k], 1);
        slot2[e] = atomicAdd(&deg2[k], 1);
    }
}

__device__ __forceinline__ int wave_incl_scan(int x, int lane) {
#pragma unroll
    for (int off = 1; off < 64; off <<= 1) {
        const int v = __shfl_up(x, off);
        if (lane >= off) x += v;
    }
    return x;
}

__device__ __forceinline__ int4 load_deg4(const int* __restrict__ d, int idx) {
    if (idx + 3 < NS) return *(const int4*)(d + idx);
    int4 v = make_int4(0, 0, 0, 0);
    if (idx + 0 < NS) v.x = d[idx + 0];
    if (idx + 1 < NS) v.y = d[idx + 1];
    if (idx + 2 < NS) v.z = d[idx + 2];
    if (idx + 3 < NS) v.w = d[idx + 3];
    return v;
}

__global__ __launch_bounds__(256) void k_scan1(const int* __restrict__ deg,
                                               int* __restrict__ psum) {
    const int conv = blockIdx.y, blk = blockIdx.x, t = threadIdx.x;
    const int* d = deg + conv * NS;
    const int4 v = load_deg4(d, blk * 1024 + t * 4);
    int s = v.x + v.y + v.z + v.w;
#pragma unroll
    for (int m = 32; m; m >>= 1) s += __shfl_xor(s, m);
    __shared__ int wsum[4];
    const int lane = t & 63, wv = t >> 6;
    if (lane == 0) wsum[wv] = s;
    __syncthreads();
    if (t == 0) psum[conv * 64 + blk] = wsum[0] + wsum[1] + wsum[2] + wsum[3];
}

__global__ __launch_bounds__(128) void k_scan2(const int* __restrict__ psum,
                                               int* __restrict__ pref) {
    const int t = threadIdx.x;
    const int w = t >> 6, lane = t & 63;
    const int x = (lane < 49) ? psum[w * 64 + lane] : 0;
    const int incl = wave_incl_scan(x, lane);
    if (lane < 49) pref[w * 64 + lane] = incl - x;
}

__global__ __launch_bounds__(256) void k_scan3(const int* __restrict__ deg,
                                               const int* __restrict__ pref,
                                               int* __restrict__ rp1, int* __restrict__ rp2) {
    const int conv = blockIdx.y, blk = blockIdx.x, t = threadIdx.x;
    const int* d = deg + conv * NS;
    int* rp = conv ? rp2 : rp1;
    const int idx = blk * 1024 + t * 4;
    const int4 v = load_deg4(d, idx);
    const int tsum = v.x + v.y + v.z + v.w;
    const int lane = t & 63, wv = t >> 6;
    const int incl = wave_incl_scan(tsum, lane);
    __shared__ int wsum[4];
    if (lane == 63) wsum[wv] = incl;
    __syncthreads();
    int woff = 0;
#pragma unroll
    for (int i = 0; i < 4; i++) woff += (i < wv) ? wsum[i] : 0;
    int ex = pref[conv * 64 + blk] + woff + (incl - tsum);
    if (idx + 0 < NS) rp[idx + 0] = ex; ex += v.x;
    if (idx + 1 < NS) rp[idx + 1] = ex; ex += v.y;
    if (idx + 2 < NS) rp[idx + 2] = ex; ex += v.z;
    if (idx + 3 < NS) rp[idx + 3] = ex; ex += v.w;
    if (blk == 48 && t == 0)
        rp[NS] = pref[conv * 64 + 48] + wsum[0] + wsum[1] + wsum[2] + wsum[3];
}

// ---------------------------------------------------------------------------
// Gather: one wave per dst node; 4 groups x 16 lanes; group g owns edge quads
// {beg+4g+16t..+3}. ee recomputed in-place: a_d[dst] is wave-uniform,
// a_s[src] is a broadcast 4B load; exp on the otherwise-idle VALU.
// ---------------------------------------------------------------------------
__device__ __forceinline__ void fma8(float acc[8], float e, const uint4 q) {
    acc[0] += e * __uint_as_float(q.x << 16);
    acc[1] += e * __uint_as_float(q.x & 0xFFFF0000u);
    acc[2] += e * __uint_as_float(q.y << 16);
    acc[3] += e * __uint_as_float(q.y & 0xFFFF0000u);
    acc[4] += e * __uint_as_float(q.z << 16);
    acc[5] += e * __uint_as_float(q.z & 0xFFFF0000u);
    acc[6] += e * __uint_as_float(q.w << 16);
    acc[7] += e * __uint_as_float(q.w & 0xFFFF0000u);
}

__global__ __launch_bounds__(256) void k_gather(
    const int* __restrict__ rp1, const int* __restrict__ rec1, const ushort* __restrict__ h1,
    const float* __restrict__ as1, const float* __restrict__ ad1,
    const int* __restrict__ rp2, const int* __restrict__ rec2, const ushort* __restrict__ h2,
    const float* __restrict__ as2, const float* __restrict__ ad2,
    float* __restrict__ out) {
    const int conv = blockIdx.y;
    const int* rp = conv ? rp2 : rp1;
    const int* rec = conv ? rec2 : rec1;
    const ushort* h = conv ? h2 : h1;
    const float* as_ = conv ? as2 : as1;
    const float* ad_ = conv ? ad2 : ad1;
    float* outb = conv ? out : out + (size_t)NS * DD;  // conv1 -> rows [NS,N)
    const int node = blockIdx.x * 4 + (threadIdx.x >> 6);
    const int gd = conv ? node : node + NS;            // global dst index
    const int lane = threadIdx.x & 63;
    const int g = lane >> 4, l16 = lane & 15;
    const int beg = rp[node], end = rp[node + 1];
    const float adv = ad_[gd];
    float acc[8];
#pragma unroll
    for (int i = 0; i < 8; i++) acc[i] = 0.f;
    float es = 0.f;

    for (int e0 = beg + g * 4; e0 < end; e0 += 16) {
        int s[4];
#pragma unroll
        for (int u = 0; u < 4; u++)
            s[u] = (e0 + u < end) ? rec[e0 + u] : 0;
        uint4 q[4];
#pragma unroll
        for (int u = 0; u < 4; u++)
            q[u] = *(const uint4*)(h + (size_t)s[u] * DD + l16 * 8);
        float w[4];
#pragma unroll
        for (int u = 0; u < 4; u++) {
            float ev = as_[s[u]] + adv;
            ev = ev > 0.f ? ev : 0.2f * ev;
            w[u] = (e0 + u < end) ? __expf(ev) : 0.f;
        }
#pragma unroll
        for (int u = 0; u < 4; u++) {
            es += w[u];
            fma8(acc, w[u], q[u]);
        }
    }

    // reduce across the 4 groups
#pragma unroll
    for (int i = 0; i < 8; i++) {
        acc[i] += __shfl_xor(acc[i], 16);
        acc[i] += __shfl_xor(acc[i], 32);
    }
    es += __shfl_xor(es, 16);
    es += __shfl_xor(es, 32);

    if (g == 0) {
        const float inv = 1.f / (es + 1e-16f);
        float4 o0, o1;
        o0.x = fmaxf(acc[0] * inv, 0.f);
        o0.y = fmaxf(acc[1] * inv, 0.f);
        o0.z = fmaxf(acc[2] * inv, 0.f);
        o0.w = fmaxf(acc[3] * inv, 0.f);
        o1.x = fmaxf(acc[4] * inv, 0.f);
        o1.y = fmaxf(acc[5] * inv, 0.f);
        o1.z = fmaxf(acc[6] * inv, 0.f);
        o1.w = fmaxf(acc[7] * inv, 0.f);
        *(float4*)(outb + (size_t)node * DD + l16 * 8) = o0;
        *(float4*)(outb + (size_t)node * DD + l16 * 8 + 4) = o1;
    }
}

extern "C" void kernel_launch(void* const* d_in, const int* in_sizes, int n_in,
                              void* d_out, int out_size, void* d_ws, size_t ws_size,
                              hipStream_t stream) {
    const int* ei  = (const int*)d_in[0];
    const int* pei = (const int*)d_in[1];
    const int* aei = (const int*)d_in[2];
    const float* xs  = (const float*)d_in[3];
    const float* xt  = (const float*)d_in[4];
    const float* Ws  = (const float*)d_in[5];
    const float* bs  = (const float*)d_in[6];
    const float* Wt  = (const float*)d_in[7];
    const float* bt  = (const float*)d_in[8];
    const float* W1  = (const float*)d_in[9];
    const float* a1s = (const float*)d_in[10];
    const float* a1d = (const float*)d_in[11];
    const float* W2  = (const float*)d_in[12];
    const float* a2s = (const float*)d_in[13];
    const float* a2d = (const float*)d_in[14];
    float* ws  = (float*)d_ws;
    float* out = (float*)d_out;

    ushort* h1 = (ushort*)(ws + OFF_H1);
    ushort* h2 = (ushort*)(ws + OFF_H2);
    float* as1 = ws + OFF_AS1;
    float* ad1 = ws + OFF_AD1;
    float* as2 = ws + OFF_AS2;
    float* ad2 = ws + OFF_AD2;
    int* deg1  = (int*)(ws + OFF_DEG1);
    int* rp1   = (int*)(ws + OFF_RP1);
    int* rp2   = (int*)(ws + OFF_RP2);
    int* psum  = (int*)(ws + OFF_PS);
    int* pref  = (int*)(ws + OFF_PREF);
    int* slot1 = (int*)(ws + OFF_SLOT1);
    int* slot2 = (int*)(ws + OFF_SLOT2);
    int* rec1  = (int*)(ws + OFF_REC1);
    int* rec2  = (int*)(ws + OFF_REC2);

    hipMemsetAsync(deg1, 0, 2 * NS * sizeof(int), stream);  // DEG1,DEG2 contiguous

    k_count_both<<<EDGE_BLOCKS, 256, 0, stream>>>(ei, pei, aei, deg1, deg1 + NS, slot1, slot2);
    k_scan1<<<dim3(49, 2), 256, 0, stream>>>(deg1, psum);
    k_scan2<<<1, 128, 0, stream>>>(psum, pref);
    k_scan3<<<dim3(49, 2), 256, 0, stream>>>(deg1, pref, rp1, rp2);

    k_fat<<<GEMM_BLOCKS + EDGE_BLOCKS, 256, 0, stream>>>(
        xs, xt, Ws, bs, Wt, bt, W1, a1s, a1d, W2, a2s, a2d,
        h1, h2, as1, ad1, as2, ad2,
        ei, pei, aei, rp1, rp2, slot1, slot2, rec1, rec2);

    k_gather<<<dim3(NS / 4, 2), 256, 0, stream>>>(
        rp1, rec1, h1, as1, ad1, rp2, rec2, h2, as2, ad2, out);
}

// Round 10
// 317.992 us; speedup vs baseline: 10.3369x; 1.0056x over previous
//
#include <hip/hip_runtime.h>
#include <hip/hip_bf16.h>

// Problem constants
#define E0   500000
#define NS   50000
#define DD   128
#define ETOT (2*E0 + NS)   // per-conv edges incl. self loops = 1,050,000

#define GEMM_BLOCKS 1564   // 782 row-tiles x 2 halves
#define EDGE_BLOCKS 4102   // ceil(ETOT/256)

// workspace layout (in 4B units)
#define OFF_H1    0UL          // ushort[100000*128] = 6.4M floats
#define OFF_H2    6400000UL
#define OFF_AS1   12800000UL   // float[100000]
#define OFF_AD1   12900000UL
#define OFF_AS2   13000000UL
#define OFF_AD2   13100000UL
#define OFF_DEG1  13200000UL   // int[50000]
#define OFF_DEG2  13250000UL   // contiguous with DEG1
#define OFF_RP1   13300000UL   // int[50001]
#define OFF_RP2   13351000UL
#define OFF_PS    13402000UL   // int[128]
#define OFF_PREF  13402128UL   // int[128]
#define OFF_SLOT1 13402256UL   // int[1050000]
#define OFF_SLOT2 14452256UL
#define OFF_REC1  15502256UL   // int[1050000] (src only)
#define OFF_REC2  16552256UL
// total 17,602,256 * 4B = 70.4 MB

typedef __bf16 bf16x8 __attribute__((ext_vector_type(8)));
typedef float f32x4 __attribute__((ext_vector_type(4)));

__device__ __forceinline__ ushort f2bf(float f) {
    uint b = __float_as_uint(f);
    return (ushort)((b + 0x7FFFu + ((b >> 16) & 1u)) >> 16);
}
__device__ __forceinline__ uint pk2(float a, float b) {
    return (uint)f2bf(a) | ((uint)f2bf(b) << 16);
}

// ---------------------------------------------------------------------------
// GEMM path helpers (identical math to the proven kernel)
// ---------------------------------------------------------------------------
__device__ __forceinline__ void stage_w_bf16(ushort* Wl, const float* __restrict__ W, int tid) {
#pragma unroll
    for (int i = 0; i < 8; i++) {
        const int idx = i * 256 + tid;          // 2048 chunks of 16B
        const int row = idx >> 4, ch = idx & 15;
        const float4 f0 = *(const float4*)(W + row * DD + ch * 8);
        const float4 f1 = *(const float4*)(W + row * DD + ch * 8 + 4);
        uint4 v = make_uint4(pk2(f0.x, f0.y), pk2(f0.z, f0.w), pk2(f1.x, f1.y), pk2(f1.z, f1.w));
        *(uint4*)((char*)Wl + ((row * 256 + ch * 16) ^ ((row & 7) << 4))) = v;
    }
}

__device__ __forceinline__ void stage_x(ushort* Xl, const float* __restrict__ xin,
                                        int row0, int tid) {
#pragma unroll
    for (int i = 0; i < 4; i++) {
        const int idx = i * 256 + tid;          // 1024 chunks of 16B
        const int r = idx >> 4, ch = idx & 15;
        const int gr = row0 + r;
        float4 f0 = make_float4(0.f, 0.f, 0.f, 0.f), f1 = f0;
        if (gr < NS) {
            f0 = *(const float4*)(xin + (size_t)gr * DD + ch * 8);
            f1 = *(const float4*)(xin + (size_t)gr * DD + ch * 8 + 4);
        }
        uint4 v = make_uint4(pk2(f0.x, f0.y), pk2(f0.z, f0.w), pk2(f1.x, f1.y), pk2(f1.z, f1.w));
        *(uint4*)((char*)Xl + ((r * 256 + ch * 16) ^ ((r & 7) << 4))) = v;
    }
}

__device__ __forceinline__ void mfma_phase(const ushort* Wl, const ushort* Xl,
                                           int wrow, int lane, f32x4 acc[8]) {
    const int l15 = lane & 15, q = lane >> 4;
    bf16x8 a[4];
#pragma unroll
    for (int ks = 0; ks < 4; ks++) {
        const int row = wrow + l15;
        const int byte = (row * 256 + (ks * 32 + q * 8) * 2) ^ ((row & 7) << 4);
        a[ks] = *(const bf16x8*)((const char*)Xl + byte);
    }
#pragma unroll
    for (int nt = 0; nt < 8; nt++) {
        const int n = nt * 16 + l15;
#pragma unroll
        for (int ks = 0; ks < 4; ks++) {
            const int byte = (n * 256 + (ks * 32 + q * 8) * 2) ^ ((n & 7) << 4);
            bf16x8 b = *(const bf16x8*)((const char*)Wl + byte);
            acc[nt] = __builtin_amdgcn_mfma_f32_16x16x32_bf16(a[ks], b, acc[nt], 0, 0, 0);
        }
    }
}

__device__ __forceinline__ void epi23(const f32x4 acc[8], int half, int row0, int wrow,
                                      int lane, const float* __restrict__ avs,
                                      const float* __restrict__ avd,
                                      ushort* __restrict__ h,
                                      float* __restrict__ as_, float* __restrict__ ad_) {
    const int l15 = lane & 15, q = lane >> 4;
    float vs[8], vd[8];
#pragma unroll
    for (int nt = 0; nt < 8; nt++) { vs[nt] = avs[nt * 16 + l15]; vd[nt] = avd[nt * 16 + l15]; }
#pragma unroll
    for (int r = 0; r < 4; r++) {
        const int gr = row0 + wrow + q * 4 + r;
        const bool ok = gr < NS;
        const size_t node = (size_t)(half * NS + gr);
        float ps = 0.f, pd = 0.f;
#pragma unroll
        for (int nt = 0; nt < 8; nt++) {
            const float v = acc[nt][r];
            ps += v * vs[nt];
            pd += v * vd[nt];
            if (ok) h[node * DD + nt * 16 + l15] = f2bf(v);
        }
#pragma unroll
        for (int m = 8; m; m >>= 1) { ps += __shfl_xor(ps, m); pd += __shfl_xor(pd, m); }
        if (ok && l15 == 0) { as_[node] = ps; ad_[node] = pd; }
    }
}

// ---------------------------------------------------------------------------
// FAT kernel: blocks [0, GEMM_BLOCKS) run the fused dense GEMM; blocks
// [GEMM_BLOCKS, ...) run COUNT (deg histogram + slot = atomic return),
// hidden under the MFMA-bound gemm. Neither path depends on the other.
// ---------------------------------------------------------------------------
__global__ __launch_bounds__(256) void k_fat(
    const float* __restrict__ xs, const float* __restrict__ xt,
    const float* __restrict__ Ws, const float* __restrict__ bs,
    const float* __restrict__ Wt, const float* __restrict__ bt,
    const float* __restrict__ W1, const float* __restrict__ a1s, const float* __restrict__ a1d,
    const float* __restrict__ W2, const float* __restrict__ a2s, const float* __restrict__ a2d,
    ushort* __restrict__ h1, ushort* __restrict__ h2,
    float* __restrict__ as1, float* __restrict__ ad1,
    float* __restrict__ as2, float* __restrict__ ad2,
    const int* __restrict__ ei, const int* __restrict__ pei, const int* __restrict__ aei,
    int* __restrict__ deg1, int* __restrict__ deg2,
    int* __restrict__ slot1, int* __restrict__ slot2) {
    __shared__ __align__(16) ushort Wl[128 * 128];  // 32 KB
    __shared__ __align__(16) ushort Xl[64 * 128];   // 16 KB
    const int bid = blockIdx.x;
    const int tid = threadIdx.x;

    if (bid >= GEMM_BLOCKS) {
        // ---------------- count path ----------------
        const int e = (bid - GEMM_BLOCKS) * 256 + tid;
        if (e >= ETOT) return;
        if (e < E0) {
            const int a = ei[e], b = ei[E0 + e];
            slot1[e] = atomicAdd(&deg1[b], 1);
            slot2[e] = atomicAdd(&deg2[a], 1);
        } else if (e < 2 * E0) {
            const int k = e - E0;
            const int d1 = aei[E0 + k];
            if (d1 >= NS) slot1[e] = atomicAdd(&deg1[d1 - NS], 1);
            const int d2 = pei[E0 + k];
            if (d2 < NS) slot2[e] = atomicAdd(&deg2[d2], 1);
        } else {
            const int k = e - 2 * E0;
            slot1[e] = atomicAdd(&deg1[k], 1);
            slot2[e] = atomicAdd(&deg2[k], 1);
        }
        return;
    }

    // ---------------- gemm path (identical to proven kernel) ----------------
    const int lane = tid & 63, wv = tid >> 6, wrow = wv * 16;
    const int l15 = lane & 15, q = lane >> 4;
    const int half = (bid >= 782) ? 1 : 0;
    const int row0 = (bid - half * 782) * 64;
    const float* xin = half ? xt : xs;
    const float* W0  = half ? Wt : Ws;
    const float* b0  = half ? bt : bs;

    stage_w_bf16(Wl, W0, tid);
    stage_x(Xl, xin, row0, tid);
    __syncthreads();

    f32x4 acc[8];
#pragma unroll
    for (int nt = 0; nt < 8; nt++) acc[nt] = 0.f;
    mfma_phase(Wl, Xl, wrow, lane, acc);

#pragma unroll
    for (int nt = 0; nt < 8; nt++) {
        const float bvv = b0[nt * 16 + l15];
#pragma unroll
        for (int r = 0; r < 4; r++) {
            const int row = wrow + q * 4 + r;
            const int byte = (row * 256 + (nt * 16 + l15) * 2) ^ ((row & 7) << 4);
            *(ushort*)((char*)Xl + byte) = f2bf(acc[nt][r] + bvv);
        }
    }
    __syncthreads();
    stage_w_bf16(Wl, W1, tid);
    __syncthreads();

#pragma unroll
    for (int nt = 0; nt < 8; nt++) acc[nt] = 0.f;
    mfma_phase(Wl, Xl, wrow, lane, acc);
    epi23(acc, half, row0, wrow, lane, a1s, a1d, h1, as1, ad1);

    __syncthreads();
    stage_w_bf16(Wl, W2, tid);
    __syncthreads();

#pragma unroll
    for (int nt = 0; nt < 8; nt++) acc[nt] = 0.f;
    mfma_phase(Wl, Xl, wrow, lane, acc);
    epi23(acc, half, row0, wrow, lane, a2s, a2d, h2, as2, ad2);
}

__device__ __forceinline__ int wave_incl_scan(int x, int lane) {
#pragma unroll
    for (int off = 1; off < 64; off <<= 1) {
        const int v = __shfl_up(x, off);
        if (lane >= off) x += v;
    }
    return x;
}

__device__ __forceinline__ int4 load_deg4(const int* __restrict__ d, int idx) {
    if (idx + 3 < NS) return *(const int4*)(d + idx);
    int4 v = make_int4(0, 0, 0, 0);
    if (idx + 0 < NS) v.x = d[idx + 0];
    if (idx + 1 < NS) v.y = d[idx + 1];
    if (idx + 2 < NS) v.z = d[idx + 2];
    if (idx + 3 < NS) v.w = d[idx + 3];
    return v;
}

__global__ __launch_bounds__(256) void k_scan1(const int* __restrict__ deg,
                                               int* __restrict__ psum) {
    const int conv = blockIdx.y, blk = blockIdx.x, t = threadIdx.x;
    const int* d = deg + conv * NS;
    const int4 v = load_deg4(d, blk * 1024 + t * 4);
    int s = v.x + v.y + v.z + v.w;
#pragma unroll
    for (int m = 32; m; m >>= 1) s += __shfl_xor(s, m);
    __shared__ int wsum[4];
    const int lane = t & 63, wv = t >> 6;
    if (lane == 0) wsum[wv] = s;
    __syncthreads();
    if (t == 0) psum[conv * 64 + blk] = wsum[0] + wsum[1] + wsum[2] + wsum[3];
}

__global__ __launch_bounds__(128) void k_scan2(const int* __restrict__ psum,
                                               int* __restrict__ pref) {
    const int t = threadIdx.x;
    const int w = t >> 6, lane = t & 63;
    const int x = (lane < 49) ? psum[w * 64 + lane] : 0;
    const int incl = wave_incl_scan(x, lane);
    if (lane < 49) pref[w * 64 + lane] = incl - x;
}

__global__ __launch_bounds__(256) void k_scan3(const int* __restrict__ deg,
                                               const int* __restrict__ pref,
                                               int* __restrict__ rp1, int* __restrict__ rp2) {
    const int conv = blockIdx.y, blk = blockIdx.x, t = threadIdx.x;
    const int* d = deg + conv * NS;
    int* rp = conv ? rp2 : rp1;
    const int idx = blk * 1024 + t * 4;
    const int4 v = load_deg4(d, idx);
    const int tsum = v.x + v.y + v.z + v.w;
    const int lane = t & 63, wv = t >> 6;
    const int incl = wave_incl_scan(tsum, lane);
    __shared__ int wsum[4];
    if (lane == 63) wsum[wv] = incl;
    __syncthreads();
    int woff = 0;
#pragma unroll
    for (int i = 0; i < 4; i++) woff += (i < wv) ? wsum[i] : 0;
    int ex = pref[conv * 64 + blk] + woff + (incl - tsum);
    if (idx + 0 < NS) rp[idx + 0] = ex; ex += v.x;
    if (idx + 1 < NS) rp[idx + 1] = ex; ex += v.y;
    if (idx + 2 < NS) rp[idx + 2] = ex; ex += v.z;
    if (idx + 3 < NS) rp[idx + 3] = ex; ex += v.w;
    if (blk == 48 && t == 0)
        rp[NS] = pref[conv * 64 + 48] + wsum[0] + wsum[1] + wsum[2] + wsum[3];
}

// ---------------------------------------------------------------------------
// Fill: atomic-free CSR placement (pos = rp[dst] + slot[e]); no LDS -> full
// occupancy.
// ---------------------------------------------------------------------------
__global__ __launch_bounds__(256) void k_fill(
    const int* __restrict__ ei, const int* __restrict__ pei, const int* __restrict__ aei,
    const int* __restrict__ rp1, const int* __restrict__ rp2,
    const int* __restrict__ slot1, const int* __restrict__ slot2,
    int* __restrict__ rec1, int* __restrict__ rec2) {
    const int e = blockIdx.x * 256 + threadIdx.x;
    if (e >= ETOT) return;
    if (e < E0) {
        const int a = ei[e], b = ei[E0 + e];
        rec1[rp1[b] + slot1[e]] = a;          // conv1: s=a, dl=b
        rec2[rp2[a] + slot2[e]] = b + NS;     // conv2: s=b+NS, dl=a
    } else if (e < 2 * E0) {
        const int k = e - E0;
        const int s1 = aei[k], d1 = aei[E0 + k];
        if (d1 >= NS) rec1[rp1[d1 - NS] + slot1[e]] = s1;
        const int s2 = pei[k], d2 = pei[E0 + k];
        if (d2 < NS) rec2[rp2[d2] + slot2[e]] = s2;
    } else {
        const int k = e - 2 * E0;
        rec1[rp1[k] + slot1[e]] = NS + k;
        rec2[rp2[k] + slot2[e]] = k;
    }
}

// ---------------------------------------------------------------------------
// Gather: one wave per dst node; 4 groups x 16 lanes; group g owns edge quads
// {beg+4g+16t..+3}. ee recomputed in-place (a_d wave-uniform, a_s broadcast).
// ---------------------------------------------------------------------------
__device__ __forceinline__ void fma8(float acc[8], float e, const uint4 q) {
    acc[0] += e * __uint_as_float(q.x << 16);
    acc[1] += e * __uint_as_float(q.x & 0xFFFF0000u);
    acc[2] += e * __uint_as_float(q.y << 16);
    acc[3] += e * __uint_as_float(q.y & 0xFFFF0000u);
    acc[4] += e * __uint_as_float(q.z << 16);
    acc[5] += e * __uint_as_float(q.z & 0xFFFF0000u);
    acc[6] += e * __uint_as_float(q.w << 16);
    acc[7] += e * __uint_as_float(q.w & 0xFFFF0000u);
}

__global__ __launch_bounds__(256) void k_gather(
    const int* __restrict__ rp1, const int* __restrict__ rec1, const ushort* __restrict__ h1,
    const float* __restrict__ as1, const float* __restrict__ ad1,
    const int* __restrict__ rp2, const int* __restrict__ rec2, const ushort* __restrict__ h2,
    const float* __restrict__ as2, const float* __restrict__ ad2,
    float* __restrict__ out) {
    const int conv = blockIdx.y;
    const int* rp = conv ? rp2 : rp1;
    const int* rec = conv ? rec2 : rec1;
    const ushort* h = conv ? h2 : h1;
    const float* as_ = conv ? as2 : as1;
    const float* ad_ = conv ? ad2 : ad1;
    float* outb = conv ? out : out + (size_t)NS * DD;  // conv1 -> rows [NS,N)
    const int node = blockIdx.x * 4 + (threadIdx.x >> 6);
    const int gd = conv ? node : node + NS;            // global dst index
    const int lane = threadIdx.x & 63;
    const int g = lane >> 4, l16 = lane & 15;
    const int beg = rp[node], end = rp[node + 1];
    const float adv = ad_[gd];
    float acc[8];
#pragma unroll
    for (int i = 0; i < 8; i++) acc[i] = 0.f;
    float es = 0.f;

    for (int e0 = beg + g * 4; e0 < end; e0 += 16) {
        int s[4];
#pragma unroll
        for (int u = 0; u < 4; u++)
            s[u] = (e0 + u < end) ? rec[e0 + u] : 0;
        uint4 q[4];
#pragma unroll
        for (int u = 0; u < 4; u++)
            q[u] = *(const uint4*)(h + (size_t)s[u] * DD + l16 * 8);
        float w[4];
#pragma unroll
        for (int u = 0; u < 4; u++) {
            float ev = as_[s[u]] + adv;
            ev = ev > 0.f ? ev : 0.2f * ev;
            w[u] = (e0 + u < end) ? __expf(ev) : 0.f;
        }
#pragma unroll
        for (int u = 0; u < 4; u++) {
            es += w[u];
            fma8(acc, w[u], q[u]);
        }
    }

    // reduce across the 4 groups
#pragma unroll
    for (int i = 0; i < 8; i++) {
        acc[i] += __shfl_xor(acc[i], 16);
        acc[i] += __shfl_xor(acc[i], 32);
    }
    es += __shfl_xor(es, 16);
    es += __shfl_xor(es, 32);

    if (g == 0) {
        const float inv = 1.f / (es + 1e-16f);
        float4 o0, o1;
        o0.x = fmaxf(acc[0] * inv, 0.f);
        o0.y = fmaxf(acc[1] * inv, 0.f);
        o0.z = fmaxf(acc[2] * inv, 0.f);
        o0.w = fmaxf(acc[3] * inv, 0.f);
        o1.x = fmaxf(acc[4] * inv, 0.f);
        o1.y = fmaxf(acc[5] * inv, 0.f);
        o1.z = fmaxf(acc[6] * inv, 0.f);
        o1.w = fmaxf(acc[7] * inv, 0.f);
        *(float4*)(outb + (size_t)node * DD + l16 * 8) = o0;
        *(float4*)(outb + (size_t)node * DD + l16 * 8 + 4) = o1;
    }
}

extern "C" void kernel_launch(void* const* d_in, const int* in_sizes, int n_in,
                              void* d_out, int out_size, void* d_ws, size_t ws_size,
                              hipStream_t stream) {
    const int* ei  = (const int*)d_in[0];
    const int* pei = (const int*)d_in[1];
    const int* aei = (const int*)d_in[2];
    const float* xs  = (const float*)d_in[3];
    const float* xt  = (const float*)d_in[4];
    const float* Ws  = (const float*)d_in[5];
    const float* bs  = (const float*)d_in[6];
    const float* Wt  = (const float*)d_in[7];
    const float* bt  = (const float*)d_in[8];
    const float* W1  = (const float*)d_in[9];
    const float* a1s = (const float*)d_in[10];
    const float* a1d = (const float*)d_in[11];
    const float* W2  = (const float*)d_in[12];
    const float* a2s = (const float*)d_in[13];
    const float* a2d = (const float*)d_in[14];
    float* ws  = (float*)d_ws;
    float* out = (float*)d_out;

    ushort* h1 = (ushort*)(ws + OFF_H1);
    ushort* h2 = (ushort*)(ws + OFF_H2);
    float* as1 = ws + OFF_AS1;
    float* ad1 = ws + OFF_AD1;
    float* as2 = ws + OFF_AS2;
    float* ad2 = ws + OFF_AD2;
    int* deg1  = (int*)(ws + OFF_DEG1);
    int* rp1   = (int*)(ws + OFF_RP1);
    int* rp2   = (int*)(ws + OFF_RP2);
    int* psum  = (int*)(ws + OFF_PS);
    int* pref  = (int*)(ws + OFF_PREF);
    int* slot1 = (int*)(ws + OFF_SLOT1);
    int* slot2 = (int*)(ws + OFF_SLOT2);
    int* rec1  = (int*)(ws + OFF_REC1);
    int* rec2  = (int*)(ws + OFF_REC2);

    hipMemsetAsync(deg1, 0, 2 * NS * sizeof(int), stream);  // DEG1,DEG2 contiguous

    // gemm (blocks 0..1563) overlapped with count (blocks 1564..)
    k_fat<<<GEMM_BLOCKS + EDGE_BLOCKS, 256, 0, stream>>>(
        xs, xt, Ws, bs, Wt, bt, W1, a1s, a1d, W2, a2s, a2d,
        h1, h2, as1, ad1, as2, ad2,
        ei, pei, aei, deg1, deg1 + NS, slot1, slot2);

    k_scan1<<<dim3(49, 2), 256, 0, stream>>>(deg1, psum);
    k_scan2<<<1, 128, 0, stream>>>(psum, pref);
    k_scan3<<<dim3(49, 2), 256, 0, stream>>>(deg1, pref, rp1, rp2);

    k_fill<<<EDGE_BLOCKS, 256, 0, stream>>>(ei, pei, aei, rp1, rp2, slot1, slot2, rec1, rec2);

    k_gather<<<dim3(NS / 4, 2), 256, 0, stream>>>(
        rp1, rec1, h1, as1, ad1, rp2, rec2, h2, as2, ad2, out);
}